// Round 14
// baseline (1233.250 us; speedup 1.0000x reference)
//
#include <hip/hip_runtime.h>

#define N_NODES 8000
#define FEAT 64
#define HID 128
#define LOOKBACK 12
#define CAP 64
#define NBLK 500
#define NGROUPS 32     // ceil(500/16), last group has 4 blocks

// ---------------- zero counters + barrier words ----------------
__global__ __launch_bounds__(256)
void zero_kernel(int* __restrict__ cnt, unsigned* __restrict__ bar) {
    int g = blockIdx.x * 256 + threadIdx.x;
    if (g < N_NODES) cnt[g] = 0;
    if (g < 4096) bar[g] = 0u;
}

// ---------------- adjacency extraction: grid-strided (R12, verified) ----------------
__global__ __launch_bounds__(256)
void build_adj_kernel(const float* __restrict__ adj, int* __restrict__ cnt,
                      int* __restrict__ lists) {
    const long NQ = (long)N_NODES * N_NODES / 4;
    const long STRIDE = 2048L * 256;
    for (long q = (long)blockIdx.x * 256 + threadIdx.x; q < NQ; q += STRIDE) {
        float4 w = *reinterpret_cast<const float4*>(adj + 4 * q);
        if (w.x != 0.0f || w.y != 0.0f || w.z != 0.0f || w.w != 0.0f) {
            int i  = (int)(q / (N_NODES / 4));
            int j0 = (int)(q % (N_NODES / 4)) * 4;
            float wv[4] = {w.x, w.y, w.z, w.w};
            #pragma unroll
            for (int c = 0; c < 4; ++c) {
                if (wv[c] != 0.0f) {
                    int j = j0 + c;
                    int p = atomicAdd(&cnt[j], 1);
                    if (p < CAP) lists[(long)j * CAP + p] = i;
                }
            }
        }
    }
}

// ---------------- grid barrier v3: tree + monotonic phases + s_sleep backoff ----
// R13 post-mortem: flat RMW barrier is COHERENT (output bit-identical) but 255
// spinners RMW-polling one line serialize at ~75ns -> ~80us/barrier. Tree:
// 32 groups x <=16 blocks; arr[g], rel[g] on separate 128B lines; s_sleep(32)
// (~0.85us) between polls -> <=16 spinners/line at ~1 poll/us each. Monotonic
// counters (no resets -> no reset races). SYSTEM-scope RMW (R13-proven).
__device__ __forceinline__ void gsync(unsigned* __restrict__ bar, unsigned phase) {
    __syncthreads();
    if (threadIdx.x == 0) {
        const int g   = blockIdx.x >> 4;
        const int gsz = (g < NGROUPS - 1) ? 16 : (NBLK - (NGROUPS - 1) * 16);
        unsigned* arr  = bar + g * 32;            // group arrival counters
        unsigned* root = bar + 1024;              // root counter
        unsigned* rel  = bar + 2048 + g * 32;     // group release words
        __threadfence_system();
        unsigned a = __hip_atomic_fetch_add(arr, 1u, __ATOMIC_ACQ_REL,
                                            __HIP_MEMORY_SCOPE_SYSTEM);
        bool root_completer = false;
        if (a == phase * (unsigned)gsz + (unsigned)(gsz - 1)) {
            unsigned r = __hip_atomic_fetch_add(root, 1u, __ATOMIC_ACQ_REL,
                                                __HIP_MEMORY_SCOPE_SYSTEM);
            if (r == phase * (unsigned)NGROUPS + (unsigned)(NGROUPS - 1)) {
                root_completer = true;
                for (int g2 = 0; g2 < NGROUPS; ++g2)
                    __hip_atomic_fetch_add(bar + 2048 + g2 * 32, 1u,
                                           __ATOMIC_RELEASE, __HIP_MEMORY_SCOPE_SYSTEM);
            }
        }
        if (!root_completer) {
            long it = 0;
            while (__hip_atomic_fetch_add(rel, 0u, __ATOMIC_ACQUIRE,
                                          __HIP_MEMORY_SCOPE_SYSTEM) < phase + 1) {
                __builtin_amdgcn_s_sleep(32);     // ~2048 cy backoff
                if (++it > (1L << 18)) break;     // true-deadlock escape only
            }
        }
    }
    __syncthreads();
    __threadfence();
}

// ---------------- persistent mega-kernel: sort + weights + init + 3 Euler steps ----
// 500 blocks x 256 threads (61KB LDS -> 2/CU, all co-resident). Direct mapping:
// block owns nodes [bid*16, bid*16+16). Phase bodies verbatim R12 -> bit-identical.
__global__ __launch_bounds__(256, 2)
void mega_kernel(const float* __restrict__ tspan, const float* __restrict__ x,
                 const float* __restrict__ We1, const float* __restrict__ be1,
                 const float* __restrict__ We2, const float* __restrict__ be2,
                 const float* __restrict__ Wf1, const float* __restrict__ bf1,
                 const float* __restrict__ Wf2, const float* __restrict__ bf2,
                 const float* __restrict__ Wl1, const float* __restrict__ bl1,
                 const float* __restrict__ Wr1,
                 const float* __restrict__ Wl2, const float* __restrict__ bl2,
                 const float* __restrict__ Wr2,
                 int* __restrict__ cnt, int* __restrict__ lists,
                 float* __restrict__ degf,
                 float* __restrict__ Ws1, float* __restrict__ Wc2,
                 float* __restrict__ pl, float* __restrict__ q,
                 float* __restrict__ out, unsigned* __restrict__ bar) {
    __shared__ float v[16][132];
    __shared__ float rr[16][132];
    __shared__ float tt[16][132];
    __shared__ float xsl[16][68];
    __shared__ float wbuf[64 * 128];
    const int tid = threadIdx.x;
    const int bid = blockIdx.x;

    // ======== phase A: bitonic sort (16 nodes/block) + weight stacking + init ========
    {
        const int wv = tid >> 6, lane = tid & 63;
        #pragma unroll 1
        for (int r = 0; r < 4; ++r) {
            const int n = bid * 16 + wv * 4 + r;          // 500*16 == 8000
            int m = cnt[n]; if (m > CAP) m = CAP;
            int val = (lane < m) ? lists[(long)n * CAP + lane] : 0x7FFFFFFF;
            #pragma unroll
            for (int k = 2; k <= 64; k <<= 1) {
                #pragma unroll
                for (int j = k >> 1; j > 0; j >>= 1) {
                    int other = __shfl_xor(val, j);
                    bool keepMin = (((lane & j) == 0) == ((lane & k) == 0));
                    int mn = val < other ? val : other;
                    int mx = val < other ? other : val;
                    val = keepMin ? mn : mx;
                }
            }
            lists[(long)n * CAP + lane] = val;
            if (lane == 0) { cnt[n] = m; degf[n] = (float)(m > 0 ? m : 1); }
        }
        const int gid = bid * 256 + tid;                  // 128000 threads
        if (gid < 128 * 128) {                            // Ws1 = [Wl1;Wr1]
            int k = gid >> 7, j = gid & 127;
            Ws1[gid] = (k < 64) ? Wl1[k * 128 + j] : Wr1[(k - 64) * 128 + j];
        } else if (gid < 2 * 128 * 128) {                 // Wc2 = [Wl2 | Wr2]
            int w = gid - 128 * 128;
            int k = w >> 7, j = w & 127;
            Wc2[w] = (j < 64) ? Wl2[k * 64 + j] : Wr2[k * 64 + (j - 64)];
        }
        // ---- init encoder (tables in wbuf), 4 elems/thread, exact cover ----
        float* sW1T = wbuf;
        float* sB1  = wbuf + 1536;
        float* sW2  = wbuf + 1664;
        __syncthreads();
        for (int e = tid; e < HID * LOOKBACK; e += 256) {
            int l = e / HID, hh = e % HID;
            sW1T[hh * LOOKBACK + l] = We1[e];
        }
        for (int e = tid; e < HID; e += 256) { sB1[e] = be1[e]; sW2[e] = We2[e]; }
        __syncthreads();
        int g = (bid * 256 + tid) * 4;                    // 128000*4 == N*F
        float xv[4][LOOKBACK];
        #pragma unroll
        for (int l = 0; l < LOOKBACK; ++l) {
            float4 vv = *reinterpret_cast<const float4*>(x + (long)l * N_NODES * FEAT + g);
            xv[0][l] = vv.x; xv[1][l] = vv.y; xv[2][l] = vv.z; xv[3][l] = vv.w;
        }
        float b2 = be2[0];
        float acc[4] = {b2, b2, b2, b2};
        for (int hh = 0; hh < HID; ++hh) {
            float s0 = sB1[hh], s1 = s0, s2 = s0, s3 = s0;
            #pragma unroll
            for (int l = 0; l < LOOKBACK; ++l) {
                float w = sW1T[hh * LOOKBACK + l];
                s0 += xv[0][l] * w; s1 += xv[1][l] * w;
                s2 += xv[2][l] * w; s3 += xv[3][l] * w;
            }
            float w2 = sW2[hh];
            acc[0] += fmaxf(s0, 0.0f) * w2; acc[1] += fmaxf(s1, 0.0f) * w2;
            acc[2] += fmaxf(s2, 0.0f) * w2; acc[3] += fmaxf(s3, 0.0f) * w2;
        }
        float4 o = {acc[0], acc[1], acc[2], acc[3]};
        *reinterpret_cast<float4*>(out + g) = o;
    }
    gsync(bar, 0);

    // ======== 3 Euler steps (bodies verbatim R12) ========
    const int ln = tid >> 4, jg = tid & 15;
    const int n  = bid * 16 + ln;
    const int c0 = jg * 4;
    for (int st = 0; st < 3; ++st) {
        const float* h     = out + (long)st * N_NODES * FEAT;
        float*       hnext = out + (long)(st + 1) * N_NODES * FEAT;
        // ===== sageproj =====
        {   // gather
            const int m = cnt[n];
            const int* l = lists + (long)n * CAP;
            const float inv = 1.0f / degf[n];
            float4 a = {0, 0, 0, 0};
            for (int e = 0; e < m; ++e) {
                float4 b = *reinterpret_cast<const float4*>(h + (long)l[e] * FEAT + c0);
                a.x += b.x; a.y += b.y; a.z += b.z; a.w += b.w;
            }
            float4 av = {a.x * inv, a.y * inv, a.z * inv, a.w * inv};
            *reinterpret_cast<float4*>(&v[ln][c0]) = av;
            *reinterpret_cast<float4*>(&v[ln][64 + c0]) =
                *reinterpret_cast<const float4*>(h + (long)n * FEAT + c0);
        }
        // P1
        {
            float4 b0 = *reinterpret_cast<const float4*>(bl1 + c0);
            float4 b1 = *reinterpret_cast<const float4*>(bl1 + 64 + c0);
            float A0[4] = {b0.x, b0.y, b0.z, b0.w};
            float A1[4] = {b1.x, b1.y, b1.z, b1.w};
            for (int kc = 0; kc < 2; ++kc) {
                __syncthreads();
                for (int e = tid; e < 2048; e += 256)
                    *(reinterpret_cast<float4*>(wbuf) + e) =
                        *(reinterpret_cast<const float4*>(Ws1 + kc * 8192) + e);
                __syncthreads();
                #pragma unroll 4
                for (int k = 0; k < 64; ++k) {
                    float a = v[ln][kc * 64 + k];
                    float4 w0 = *reinterpret_cast<const float4*>(&wbuf[k * 128 + c0]);
                    float4 w1 = *reinterpret_cast<const float4*>(&wbuf[k * 128 + 64 + c0]);
                    A0[0] += a * w0.x; A0[1] += a * w0.y; A0[2] += a * w0.z; A0[3] += a * w0.w;
                    A1[0] += a * w1.x; A1[1] += a * w1.y; A1[2] += a * w1.z; A1[3] += a * w1.w;
                }
            }
            float4 o0 = {fmaxf(A0[0],0.f), fmaxf(A0[1],0.f), fmaxf(A0[2],0.f), fmaxf(A0[3],0.f)};
            float4 o1 = {fmaxf(A1[0],0.f), fmaxf(A1[1],0.f), fmaxf(A1[2],0.f), fmaxf(A1[3],0.f)};
            *reinterpret_cast<float4*>(&rr[ln][c0]) = o0;
            *reinterpret_cast<float4*>(&rr[ln][64 + c0]) = o1;
        }
        // P2
        {
            float4 b0 = *reinterpret_cast<const float4*>(bf1 + c0);
            float4 b1 = *reinterpret_cast<const float4*>(bf1 + 64 + c0);
            float A0[4] = {b0.x, b0.y, b0.z, b0.w};
            float A1[4] = {b1.x, b1.y, b1.z, b1.w};
            __syncthreads();
            for (int e = tid; e < 2048; e += 256)
                *(reinterpret_cast<float4*>(wbuf) + e) =
                    *(reinterpret_cast<const float4*>(Wf1) + e);
            __syncthreads();
            #pragma unroll 4
            for (int k = 0; k < 64; ++k) {
                float a = v[ln][64 + k];
                float4 w0 = *reinterpret_cast<const float4*>(&wbuf[k * 128 + c0]);
                float4 w1 = *reinterpret_cast<const float4*>(&wbuf[k * 128 + 64 + c0]);
                A0[0] += a * w0.x; A0[1] += a * w0.y; A0[2] += a * w0.z; A0[3] += a * w0.w;
                A1[0] += a * w1.x; A1[1] += a * w1.y; A1[2] += a * w1.z; A1[3] += a * w1.w;
            }
            float4 o0 = {fmaxf(A0[0],0.f), fmaxf(A0[1],0.f), fmaxf(A0[2],0.f), fmaxf(A0[3],0.f)};
            float4 o1 = {fmaxf(A1[0],0.f), fmaxf(A1[1],0.f), fmaxf(A1[2],0.f), fmaxf(A1[3],0.f)};
            *reinterpret_cast<float4*>(&tt[ln][c0]) = o0;
            *reinterpret_cast<float4*>(&tt[ln][64 + c0]) = o1;
        }
        // P3
        {
            float4 b0 = *reinterpret_cast<const float4*>(bf2 + c0);
            float X[4] = {b0.x, b0.y, b0.z, b0.w};
            __syncthreads();
            for (int e = tid; e < 2048; e += 256)
                *(reinterpret_cast<float4*>(wbuf) + e) =
                    *(reinterpret_cast<const float4*>(Wf2) + e);
            __syncthreads();
            #pragma unroll 4
            for (int k = 0; k < 128; ++k) {
                float a = tt[ln][k];
                float4 w = *reinterpret_cast<const float4*>(&wbuf[k * 64 + c0]);
                X[0] += a * w.x; X[1] += a * w.y; X[2] += a * w.z; X[3] += a * w.w;
            }
            float4 o = {X[0], X[1], X[2], X[3]};
            *reinterpret_cast<float4*>(&xsl[ln][c0]) = o;
        }
        // P4
        {
            float P0[4] = {0, 0, 0, 0};
            float P1[4] = {0, 0, 0, 0};
            for (int kc = 0; kc < 2; ++kc) {
                __syncthreads();
                for (int e = tid; e < 2048; e += 256)
                    *(reinterpret_cast<float4*>(wbuf) + e) =
                        *(reinterpret_cast<const float4*>(Wc2 + kc * 8192) + e);
                __syncthreads();
                #pragma unroll 4
                for (int k = 0; k < 64; ++k) {
                    float a = rr[ln][kc * 64 + k];
                    float4 w0 = *reinterpret_cast<const float4*>(&wbuf[k * 128 + c0]);
                    float4 w1 = *reinterpret_cast<const float4*>(&wbuf[k * 128 + 64 + c0]);
                    P0[0] += a * w0.x; P0[1] += a * w0.y; P0[2] += a * w0.z; P0[3] += a * w0.w;
                    P1[0] += a * w1.x; P1[1] += a * w1.y; P1[2] += a * w1.z; P1[3] += a * w1.w;
                }
            }
            float4 op = {P0[0], P0[1], P0[2], P0[3]};
            *reinterpret_cast<float4*>(pl + (long)n * FEAT + c0) = op;
            float4 bv = *reinterpret_cast<const float4*>(bl2 + c0);
            float4 oq = {P1[0] + bv.x + xsl[ln][c0 + 0],
                         P1[1] + bv.y + xsl[ln][c0 + 1],
                         P1[2] + bv.z + xsl[ln][c0 + 2],
                         P1[3] + bv.w + xsl[ln][c0 + 3]};
            *reinterpret_cast<float4*>(q + (long)n * FEAT + c0) = oq;
        }
        gsync(bar, (unsigned)(2 * st + 1));
        // ===== epi =====
        {
            const int m = cnt[n];
            const int* l = lists + (long)n * CAP;
            const float inv = 1.0f / degf[n];
            float4 a = {0, 0, 0, 0};
            for (int e = 0; e < m; ++e) {
                float4 b = *reinterpret_cast<const float4*>(pl + (long)l[e] * FEAT + c0);
                a.x += b.x; a.y += b.y; a.z += b.z; a.w += b.w;
            }
            const float dt = tspan[st + 1] - tspan[st];
            float4 qv = *reinterpret_cast<const float4*>(q + (long)n * FEAT + c0);
            float4 hv = *reinterpret_cast<const float4*>(h + (long)n * FEAT + c0);
            float s0 = qv.x + a.x * inv, s1 = qv.y + a.y * inv;
            float s2 = qv.z + a.z * inv, s3 = qv.w + a.w * inv;
            s0 = fminf(fmaxf(s0, -1000.f), 1000.f); s1 = fminf(fmaxf(s1, -1000.f), 1000.f);
            s2 = fminf(fmaxf(s2, -1000.f), 1000.f); s3 = fminf(fmaxf(s3, -1000.f), 1000.f);
            float4 o = {hv.x + dt * s0, hv.y + dt * s1, hv.z + dt * s2, hv.w + dt * s3};
            *reinterpret_cast<float4*>(hnext + (long)n * FEAT + c0) = o;
        }
        if (st < 2) gsync(bar, (unsigned)(2 * st + 2));
    }
}

extern "C" void kernel_launch(void* const* d_in, const int* in_sizes, int n_in,
                              void* d_out, int out_size, void* d_ws, size_t ws_size,
                              hipStream_t stream) {
    const float* tspan = (const float*)d_in[0];
    const float* x     = (const float*)d_in[1];
    const float* adj   = (const float*)d_in[2];
    const float* We1   = (const float*)d_in[3];
    const float* be1   = (const float*)d_in[4];
    const float* We2   = (const float*)d_in[5];
    const float* be2   = (const float*)d_in[6];
    const float* Wf1   = (const float*)d_in[7];
    const float* bf1   = (const float*)d_in[8];
    const float* Wf2   = (const float*)d_in[9];
    const float* bf2   = (const float*)d_in[10];
    const float* Wl1   = (const float*)d_in[11];
    const float* bl1   = (const float*)d_in[12];
    const float* Wr1   = (const float*)d_in[13];
    const float* Wl2   = (const float*)d_in[14];
    const float* bl2   = (const float*)d_in[15];
    const float* Wr2   = (const float*)d_in[16];
    float* out = (float*)d_out;

    // workspace layout (bytes)
    char* ws = (char*)d_ws;
    int*      lists = (int*)     (ws + 0);           // 2,048,000
    int*      cnt   = (int*)     (ws + 2048000);     // 32,000
    float*    degf  = (float*)   (ws + 2080000);     // 32,000
    float*    Ws1   = (float*)   (ws + 2112000);     // 65,536
    float*    Wc2   = (float*)   (ws + 2177536);     // 65,536
    float*    pl    = (float*)   (ws + 2243072);     // 2,048,000
    float*    q     = (float*)   (ws + 4291072);     // 2,048,000
    unsigned* bar   = (unsigned*)(ws + 6339072);     // 16,384
    // total 6,355,456 bytes

    zero_kernel<<<48, 256, 0, stream>>>(cnt, bar);
    build_adj_kernel<<<2048, 256, 0, stream>>>(adj, cnt, lists);
    mega_kernel<<<NBLK, 256, 0, stream>>>(tspan, x, We1, be1, We2, be2,
                                          Wf1, bf1, Wf2, bf2,
                                          Wl1, bl1, Wr1, Wl2, bl2, Wr2,
                                          cnt, lists, degf, Ws1, Wc2,
                                          pl, q, out, bar);
}

// Round 15
// 302.264 us; speedup vs baseline: 4.0800x; 4.0800x over previous
//
#include <hip/hip_runtime.h>

#define N_NODES 8000
#define FEAT 64
#define HID 128
#define LOOKBACK 12
#define CAP 64

// ---------------- zero cnt + init encoder (independent of build) ----------------
// 500 blocks: threads 0-15 zero this block's 16 cnt entries; all 256 threads run
// the init encoder (4 elems/thread, 500*256*4 == N*F exactly).
__global__ __launch_bounds__(256)
void zero_init_kernel(int* __restrict__ cnt,
                      const float* __restrict__ x,
                      const float* __restrict__ We1, const float* __restrict__ be1,
                      const float* __restrict__ We2, const float* __restrict__ be2,
                      float* __restrict__ out0) {
    __shared__ float sW1T[HID * LOOKBACK];   // [h][l]
    __shared__ float sB1[HID];
    __shared__ float sW2[HID];
    const int tid = threadIdx.x;
    if (tid < 16) cnt[blockIdx.x * 16 + tid] = 0;
    for (int e = tid; e < HID * LOOKBACK; e += 256) {
        int l = e / HID, h = e % HID;
        sW1T[h * LOOKBACK + l] = We1[e];
    }
    for (int e = tid; e < HID; e += 256) { sB1[e] = be1[e]; sW2[e] = We2[e]; }
    __syncthreads();
    int g = (blockIdx.x * 256 + tid) * 4;
    float xv[4][LOOKBACK];
    #pragma unroll
    for (int l = 0; l < LOOKBACK; ++l) {
        float4 v = *reinterpret_cast<const float4*>(x + (long)l * N_NODES * FEAT + g);
        xv[0][l] = v.x; xv[1][l] = v.y; xv[2][l] = v.z; xv[3][l] = v.w;
    }
    float b2 = be2[0];
    float acc[4] = {b2, b2, b2, b2};
    for (int h = 0; h < HID; ++h) {
        float s0 = sB1[h], s1 = s0, s2 = s0, s3 = s0;
        #pragma unroll
        for (int l = 0; l < LOOKBACK; ++l) {
            float w = sW1T[h * LOOKBACK + l];
            s0 += xv[0][l] * w; s1 += xv[1][l] * w;
            s2 += xv[2][l] * w; s3 += xv[3][l] * w;
        }
        float w2 = sW2[h];
        acc[0] += fmaxf(s0, 0.0f) * w2; acc[1] += fmaxf(s1, 0.0f) * w2;
        acc[2] += fmaxf(s2, 0.0f) * w2; acc[3] += fmaxf(s3, 0.0f) * w2;
    }
    float4 o = {acc[0], acc[1], acc[2], acc[3]};
    *reinterpret_cast<float4*>(out0 + g) = o;
}

// ---------------- adjacency extraction: grid-strided (R12/R13-verified ~35us) ----
__global__ __launch_bounds__(256)
void build_adj_kernel(const float* __restrict__ adj, int* __restrict__ cnt,
                      int* __restrict__ lists) {
    const long NQ = (long)N_NODES * N_NODES / 4;
    const long STRIDE = 2048L * 256;
    for (long q = (long)blockIdx.x * 256 + threadIdx.x; q < NQ; q += STRIDE) {
        float4 w = *reinterpret_cast<const float4*>(adj + 4 * q);
        if (w.x != 0.0f || w.y != 0.0f || w.z != 0.0f || w.w != 0.0f) {
            int i  = (int)(q / (N_NODES / 4));
            int j0 = (int)(q % (N_NODES / 4)) * 4;
            float wv[4] = {w.x, w.y, w.z, w.w};
            #pragma unroll
            for (int c = 0; c < 4; ++c) {
                if (wv[c] != 0.0f) {
                    int j = j0 + c;
                    int p = atomicAdd(&cnt[j], 1);
                    if (p < CAP) lists[(long)j * CAP + p] = i;
                }
            }
        }
    }
}

// ---------------- fused sort + SAGE1 + proj + selfMLP ----------------
// 16 nodes/block, 500 blocks (61KB LDS -> 2/CU). lists[n]/cnt[n]/degf[n] are only
// read by the owning block, so the canonicalizing bitonic sort lives here
// (idempotent across steps). Weight chunks staged with register prefetch: next
// chunk's 8 float4 loaded during prior compute, ds_write between barriers.
// Chunk map (32KB each): 0=Wl1 1=Wr1 (P1, ==[Wl1;Wr1] rows) 2=Wf1 3=Wf2
// 4=[Wl2|Wr2] rows 0-63 col-stacked  5=rows 64-127. Identical per-output FMA
// order to R12 -> bit-identical output.
__global__ __launch_bounds__(256)
void sageproj_kernel(const float* __restrict__ h, const int* __restrict__ lists_,
                     int* __restrict__ lists, int* __restrict__ cnt,
                     float* __restrict__ degf,
                     const float* __restrict__ Wl1, const float* __restrict__ bl1,
                     const float* __restrict__ Wr1,
                     const float* __restrict__ Wl2, const float* __restrict__ bl2,
                     const float* __restrict__ Wr2,
                     const float* __restrict__ Wf1, const float* __restrict__ bf1,
                     const float* __restrict__ Wf2, const float* __restrict__ bf2,
                     float* __restrict__ pl, float* __restrict__ q) {
    __shared__ float v[16][132];     // [node][k]: k<64 aggr, k>=64 h row
    __shared__ float rr[16][132];
    __shared__ float tt[16][132];
    __shared__ float xsl[16][68];
    __shared__ float wbuf[64 * 128]; // 32 KB staged weight chunk
    const int tid = threadIdx.x;
    const int nb = blockIdx.x * 16;

    // -- register prefetch machinery --
    float4 pf[8];
    int next_chunk = 0;
    auto load_chunk = [&](int c) {
        #pragma unroll
        for (int i = 0; i < 8; ++i) {
            int e = tid + i * 256;               // float4 index 0..2047
            const float* p;
            if      (c == 0) p = Wl1 + (long)e * 4;
            else if (c == 1) p = Wr1 + (long)e * 4;
            else if (c == 2) p = Wf1 + (long)e * 4;
            else if (c == 3) p = Wf2 + (long)e * 4;
            else {
                int k  = (e >> 5) + ((c == 5) ? 64 : 0);
                int jj = e & 31;
                p = (jj < 16) ? (Wl2 + ((long)k * 16 + jj) * 4)
                              : (Wr2 + ((long)k * 16 + jj - 16) * 4);
            }
            pf[i] = *reinterpret_cast<const float4*>(p);
        }
    };
    load_chunk(next_chunk++);                    // chunk 0 hides under sort+gather

    // -- canonicalize own 16 nodes: wave-bitonic sort + deg (idempotent) --
    {
        const int wv = tid >> 6, lane = tid & 63;
        #pragma unroll 1
        for (int r = 0; r < 4; ++r) {
            const int n = nb + wv * 4 + r;
            int m = cnt[n]; if (m > CAP) m = CAP;
            int val = (lane < m) ? lists[(long)n * CAP + lane] : 0x7FFFFFFF;
            #pragma unroll
            for (int k = 2; k <= 64; k <<= 1) {
                #pragma unroll
                for (int j = k >> 1; j > 0; j >>= 1) {
                    int other = __shfl_xor(val, j);
                    bool keepMin = (((lane & j) == 0) == ((lane & k) == 0));
                    int mn = val < other ? val : other;
                    int mx = val < other ? other : val;
                    val = keepMin ? mn : mx;
                }
            }
            lists[(long)n * CAP + lane] = val;
            if (lane == 0) { cnt[n] = m; degf[n] = (float)(m > 0 ? m : 1); }
        }
    }
    __syncthreads();                             // lists/cnt/degf visible in-block

    const int ln = tid >> 4, jg = tid & 15;
    const int n  = nb + ln;
    const int c0 = jg * 4;
    {   // gather: 16 threads/node, 4 feats each
        const int m = cnt[n];
        const int* l = lists + (long)n * CAP;
        const float inv = 1.0f / degf[n];
        float4 a = {0, 0, 0, 0};
        for (int e = 0; e < m; ++e) {
            float4 b = *reinterpret_cast<const float4*>(h + (long)l[e] * FEAT + c0);
            a.x += b.x; a.y += b.y; a.z += b.z; a.w += b.w;
        }
        float4 av = {a.x * inv, a.y * inv, a.z * inv, a.w * inv};
        *reinterpret_cast<float4*>(&v[ln][c0]) = av;
        *reinterpret_cast<float4*>(&v[ln][64 + c0]) =
            *reinterpret_cast<const float4*>(h + (long)n * FEAT + c0);
    }

    // STAGE: commit prefetched chunk to wbuf, start loading the next one.
    #define STAGE()                                                          \
        do {                                                                 \
            __syncthreads();                                                 \
            _Pragma("unroll")                                                \
            for (int i = 0; i < 8; ++i)                                      \
                *(reinterpret_cast<float4*>(wbuf) + tid + i * 256) = pf[i];  \
            if (next_chunk < 6) load_chunk(next_chunk++);                    \
            __syncthreads();                                                 \
        } while (0)

    // ---- P1: rr = relu([aggr|h] @ [Wl1;Wr1] + bl1), K=128 in 2 chunks ----
    {
        float4 b0 = *reinterpret_cast<const float4*>(bl1 + c0);
        float4 b1 = *reinterpret_cast<const float4*>(bl1 + 64 + c0);
        float A0[4] = {b0.x, b0.y, b0.z, b0.w};
        float A1[4] = {b1.x, b1.y, b1.z, b1.w};
        for (int kc = 0; kc < 2; ++kc) {
            STAGE();
            #pragma unroll 4
            for (int k = 0; k < 64; ++k) {
                float a = v[ln][kc * 64 + k];
                float4 w0 = *reinterpret_cast<const float4*>(&wbuf[k * 128 + c0]);
                float4 w1 = *reinterpret_cast<const float4*>(&wbuf[k * 128 + 64 + c0]);
                A0[0] += a * w0.x; A0[1] += a * w0.y; A0[2] += a * w0.z; A0[3] += a * w0.w;
                A1[0] += a * w1.x; A1[1] += a * w1.y; A1[2] += a * w1.z; A1[3] += a * w1.w;
            }
        }
        float4 o0 = {fmaxf(A0[0],0.f), fmaxf(A0[1],0.f), fmaxf(A0[2],0.f), fmaxf(A0[3],0.f)};
        float4 o1 = {fmaxf(A1[0],0.f), fmaxf(A1[1],0.f), fmaxf(A1[2],0.f), fmaxf(A1[3],0.f)};
        *reinterpret_cast<float4*>(&rr[ln][c0]) = o0;
        *reinterpret_cast<float4*>(&rr[ln][64 + c0]) = o1;
    }
    // ---- P2: tt = relu(h @ Wf1 + bf1), K=64 ----
    {
        float4 b0 = *reinterpret_cast<const float4*>(bf1 + c0);
        float4 b1 = *reinterpret_cast<const float4*>(bf1 + 64 + c0);
        float A0[4] = {b0.x, b0.y, b0.z, b0.w};
        float A1[4] = {b1.x, b1.y, b1.z, b1.w};
        STAGE();
        #pragma unroll 4
        for (int k = 0; k < 64; ++k) {
            float a = v[ln][64 + k];
            float4 w0 = *reinterpret_cast<const float4*>(&wbuf[k * 128 + c0]);
            float4 w1 = *reinterpret_cast<const float4*>(&wbuf[k * 128 + 64 + c0]);
            A0[0] += a * w0.x; A0[1] += a * w0.y; A0[2] += a * w0.z; A0[3] += a * w0.w;
            A1[0] += a * w1.x; A1[1] += a * w1.y; A1[2] += a * w1.z; A1[3] += a * w1.w;
        }
        float4 o0 = {fmaxf(A0[0],0.f), fmaxf(A0[1],0.f), fmaxf(A0[2],0.f), fmaxf(A0[3],0.f)};
        float4 o1 = {fmaxf(A1[0],0.f), fmaxf(A1[1],0.f), fmaxf(A1[2],0.f), fmaxf(A1[3],0.f)};
        *reinterpret_cast<float4*>(&tt[ln][c0]) = o0;
        *reinterpret_cast<float4*>(&tt[ln][64 + c0]) = o1;
    }
    // ---- P3: xsl = tt @ Wf2 + bf2 (Wf2 = [128][64]) ----
    {
        float4 b0 = *reinterpret_cast<const float4*>(bf2 + c0);
        float X[4] = {b0.x, b0.y, b0.z, b0.w};
        STAGE();                                 // barrier also publishes tt
        #pragma unroll 4
        for (int k = 0; k < 128; ++k) {
            float a = tt[ln][k];
            float4 w = *reinterpret_cast<const float4*>(&wbuf[k * 64 + c0]);
            X[0] += a * w.x; X[1] += a * w.y; X[2] += a * w.z; X[3] += a * w.w;
        }
        float4 o = {X[0], X[1], X[2], X[3]};
        *reinterpret_cast<float4*>(&xsl[ln][c0]) = o;
    }
    // ---- P4: [pl|q] = rr @ [Wl2|Wr2] (+ bl2 + xsl on q half), K=128 in 2 chunks ----
    {
        float P0[4] = {0, 0, 0, 0};
        float P1[4] = {0, 0, 0, 0};
        for (int kc = 0; kc < 2; ++kc) {
            STAGE();                             // first barrier publishes xsl
            #pragma unroll 4
            for (int k = 0; k < 64; ++k) {
                float a = rr[ln][kc * 64 + k];
                float4 w0 = *reinterpret_cast<const float4*>(&wbuf[k * 128 + c0]);
                float4 w1 = *reinterpret_cast<const float4*>(&wbuf[k * 128 + 64 + c0]);
                P0[0] += a * w0.x; P0[1] += a * w0.y; P0[2] += a * w0.z; P0[3] += a * w0.w;
                P1[0] += a * w1.x; P1[1] += a * w1.y; P1[2] += a * w1.z; P1[3] += a * w1.w;
            }
        }
        float4 op = {P0[0], P0[1], P0[2], P0[3]};
        *reinterpret_cast<float4*>(pl + (long)n * FEAT + c0) = op;
        float4 bv = *reinterpret_cast<const float4*>(bl2 + c0);
        float4 oq = {P1[0] + bv.x + xsl[ln][c0 + 0],
                     P1[1] + bv.y + xsl[ln][c0 + 1],
                     P1[2] + bv.z + xsl[ln][c0 + 2],
                     P1[3] + bv.w + xsl[ln][c0 + 3]};
        *reinterpret_cast<float4*>(q + (long)n * FEAT + c0) = oq;
    }
    #undef STAGE
}

// ---------------- gather + Euler epilogue (R12 verbatim) ----------------
__global__ __launch_bounds__(256)
void epi_kernel(const float* __restrict__ pl, const float* __restrict__ q,
                const int* __restrict__ lists, const int* __restrict__ cnt,
                const float* __restrict__ degf, const float* __restrict__ hcur,
                const float* __restrict__ tspan, int step,
                float* __restrict__ hnext) {
    const int tid = threadIdx.x;
    const int ln = tid >> 4, sub = tid & 15;
    const int n = blockIdx.x * 16 + ln;
    const int f0 = sub * 4;
    const int m = cnt[n];
    const int* l = lists + (long)n * CAP;
    const float inv = 1.0f / degf[n];
    float4 a = {0, 0, 0, 0};
    for (int e = 0; e < m; ++e) {
        float4 b = *reinterpret_cast<const float4*>(pl + (long)l[e] * FEAT + f0);
        a.x += b.x; a.y += b.y; a.z += b.z; a.w += b.w;
    }
    const float dt = tspan[step + 1] - tspan[step];
    float4 qv = *reinterpret_cast<const float4*>(q + (long)n * FEAT + f0);
    float4 hv = *reinterpret_cast<const float4*>(hcur + (long)n * FEAT + f0);
    float s0 = qv.x + a.x * inv, s1 = qv.y + a.y * inv;
    float s2 = qv.z + a.z * inv, s3 = qv.w + a.w * inv;
    s0 = fminf(fmaxf(s0, -1000.f), 1000.f); s1 = fminf(fmaxf(s1, -1000.f), 1000.f);
    s2 = fminf(fmaxf(s2, -1000.f), 1000.f); s3 = fminf(fmaxf(s3, -1000.f), 1000.f);
    float4 o = {hv.x + dt * s0, hv.y + dt * s1, hv.z + dt * s2, hv.w + dt * s3};
    *reinterpret_cast<float4*>(hnext + (long)n * FEAT + f0) = o;
}

extern "C" void kernel_launch(void* const* d_in, const int* in_sizes, int n_in,
                              void* d_out, int out_size, void* d_ws, size_t ws_size,
                              hipStream_t stream) {
    const float* tspan = (const float*)d_in[0];
    const float* x     = (const float*)d_in[1];
    const float* adj   = (const float*)d_in[2];
    const float* We1   = (const float*)d_in[3];
    const float* be1   = (const float*)d_in[4];
    const float* We2   = (const float*)d_in[5];
    const float* be2   = (const float*)d_in[6];
    const float* Wf1   = (const float*)d_in[7];
    const float* bf1   = (const float*)d_in[8];
    const float* Wf2   = (const float*)d_in[9];
    const float* bf2   = (const float*)d_in[10];
    const float* Wl1   = (const float*)d_in[11];
    const float* bl1   = (const float*)d_in[12];
    const float* Wr1   = (const float*)d_in[13];
    const float* Wl2   = (const float*)d_in[14];
    const float* bl2   = (const float*)d_in[15];
    const float* Wr2   = (const float*)d_in[16];
    float* out = (float*)d_out;

    // workspace layout (bytes)
    char* ws = (char*)d_ws;
    int*   lists = (int*)  (ws + 0);           // 8000*64*4  = 2,048,000
    int*   cnt   = (int*)  (ws + 2048000);     // 32,000
    float* degf  = (float*)(ws + 2080000);     // 32,000
    float* pl    = (float*)(ws + 2112000);     // 2,048,000
    float* q     = (float*)(ws + 4160000);     // 2,048,000
    // total 6,208,000 bytes

    zero_init_kernel<<<500, 256, 0, stream>>>(cnt, x, We1, be1, We2, be2, out);
    build_adj_kernel<<<2048, 256, 0, stream>>>(adj, cnt, lists);

    for (int s = 0; s < 3; ++s) {
        const float* hcur  = out + (long)s       * N_NODES * FEAT;
        float*       hnext = out + (long)(s + 1) * N_NODES * FEAT;
        sageproj_kernel<<<500, 256, 0, stream>>>(hcur, lists, lists, cnt, degf,
                                                 Wl1, bl1, Wr1, Wl2, bl2, Wr2,
                                                 Wf1, bf1, Wf2, bf2, pl, q);
        epi_kernel<<<500, 256, 0, stream>>>(pl, q, lists, cnt, degf, hcur, tspan, s, hnext);
    }
}

// Round 16
// 284.958 us; speedup vs baseline: 4.3278x; 1.0607x over previous
//
#include <hip/hip_runtime.h>

#define N_NODES 8000
#define FEAT 64
#define HID 128
#define LOOKBACK 12
#define CAP 64

// ---------------- zero the per-node counters ----------------
__global__ __launch_bounds__(256)
void zero_cnt_kernel(int* __restrict__ cnt) {
    int g = blockIdx.x * 256 + threadIdx.x;
    if (g < N_NODES) cnt[g] = 0;
}

// ---------------- merged: build (0-2047) | init (2048-2547) | stack (2548-2675) ----
// All three sub-jobs are independent. Build = R12 grid-stride (verified ~35us,
// fills all 2048 co-resident block slots); init+stack blocks schedule into the
// build retirement tail and mostly hide.
__global__ __launch_bounds__(256)
void bis_kernel(const float* __restrict__ adj, int* __restrict__ cnt,
                int* __restrict__ lists,
                const float* __restrict__ x,
                const float* __restrict__ We1, const float* __restrict__ be1,
                const float* __restrict__ We2, const float* __restrict__ be2,
                float* __restrict__ out0,
                const float* __restrict__ Wl1, const float* __restrict__ Wr1,
                const float* __restrict__ Wl2, const float* __restrict__ Wr2,
                float* __restrict__ Ws1, float* __restrict__ Wc2) {
    __shared__ float sW1T[HID * LOOKBACK];   // [h][l]  (init branch only)
    __shared__ float sB1[HID];
    __shared__ float sW2[HID];
    const int tid = threadIdx.x;
    if (blockIdx.x < 2048) {
        // ---- grid-stride adjacency build (R12 verbatim) ----
        const long NQ = (long)N_NODES * N_NODES / 4;
        const long STRIDE = 2048L * 256;
        for (long q = (long)blockIdx.x * 256 + tid; q < NQ; q += STRIDE) {
            float4 w = *reinterpret_cast<const float4*>(adj + 4 * q);
            if (w.x != 0.0f || w.y != 0.0f || w.z != 0.0f || w.w != 0.0f) {
                int i  = (int)(q / (N_NODES / 4));
                int j0 = (int)(q % (N_NODES / 4)) * 4;
                float wv[4] = {w.x, w.y, w.z, w.w};
                #pragma unroll
                for (int c = 0; c < 4; ++c) {
                    if (wv[c] != 0.0f) {
                        int j = j0 + c;
                        int p = atomicAdd(&cnt[j], 1);
                        if (p < CAP) lists[(long)j * CAP + p] = i;
                    }
                }
            }
        }
    } else if (blockIdx.x < 2548) {
        // ---- init encoder (R12 verbatim), 4 elems/thread, exact cover ----
        const int b = blockIdx.x - 2048;
        for (int e = tid; e < HID * LOOKBACK; e += 256) {
            int l = e / HID, h = e % HID;
            sW1T[h * LOOKBACK + l] = We1[e];
        }
        for (int e = tid; e < HID; e += 256) { sB1[e] = be1[e]; sW2[e] = We2[e]; }
        __syncthreads();
        int g = (b * 256 + tid) * 4;             // 500*256*4 == N*F
        float xv[4][LOOKBACK];
        #pragma unroll
        for (int l = 0; l < LOOKBACK; ++l) {
            float4 v = *reinterpret_cast<const float4*>(x + (long)l * N_NODES * FEAT + g);
            xv[0][l] = v.x; xv[1][l] = v.y; xv[2][l] = v.z; xv[3][l] = v.w;
        }
        float b2 = be2[0];
        float acc[4] = {b2, b2, b2, b2};
        for (int h = 0; h < HID; ++h) {
            float s0 = sB1[h], s1 = s0, s2 = s0, s3 = s0;
            #pragma unroll
            for (int l = 0; l < LOOKBACK; ++l) {
                float w = sW1T[h * LOOKBACK + l];
                s0 += xv[0][l] * w; s1 += xv[1][l] * w;
                s2 += xv[2][l] * w; s3 += xv[3][l] * w;
            }
            float w2 = sW2[h];
            acc[0] += fmaxf(s0, 0.0f) * w2; acc[1] += fmaxf(s1, 0.0f) * w2;
            acc[2] += fmaxf(s2, 0.0f) * w2; acc[3] += fmaxf(s3, 0.0f) * w2;
        }
        float4 o = {acc[0], acc[1], acc[2], acc[3]};
        *reinterpret_cast<float4*>(out0 + g) = o;
    } else {
        // ---- weight stacking (R12 prep verbatim): 128 blocks x 256 == 32768 ----
        int u = (blockIdx.x - 2548) * 256 + tid;
        if (u < 128 * 128) {            // Ws1[k][j] = [Wl1;Wr1] row-stacked
            int k = u >> 7, j = u & 127;
            Ws1[u] = (k < 64) ? Wl1[k * 128 + j] : Wr1[(k - 64) * 128 + j];
        } else {                        // Wc2[k][j] = [Wl2 | Wr2] col-stacked
            int w = u - 128 * 128;
            int k = w >> 7, j = w & 127;
            Wc2[w] = (j < 64) ? Wl2[k * 64 + j] : Wr2[k * 64 + (j - 64)];
        }
    }
}

// ---------------- fused SAGE1 + proj + selfMLP (R12 verbatim + step-0 sort) ----
// 16 nodes/block, 500 blocks (2 blocks/CU). do_sort=1 only on step 0: wave-
// bitonic canonicalization (R15-proven correct) replaces the old prep kernel.
__global__ __launch_bounds__(256)
void sageproj_kernel(const float* __restrict__ h,
                     int* __restrict__ lists, int* __restrict__ cnt,
                     float* __restrict__ degf, int do_sort,
                     const float* __restrict__ Ws1, const float* __restrict__ bl1,
                     const float* __restrict__ Wc2, const float* __restrict__ bl2,
                     const float* __restrict__ Wf1, const float* __restrict__ bf1,
                     const float* __restrict__ Wf2, const float* __restrict__ bf2,
                     float* __restrict__ pl, float* __restrict__ q) {
    __shared__ float v[16][132];     // [node][k]: k<64 aggr, k>=64 h row
    __shared__ float rr[16][132];    // r1
    __shared__ float tt[16][132];    // t = relu(h@Wf1+bf1)
    __shared__ float xsl[16][68];    // xs
    __shared__ float wbuf[64 * 128]; // 32 KB weight panel chunk
    const int tid = threadIdx.x;
    const int nb = blockIdx.x * 16;
    if (do_sort) {
        const int wv = tid >> 6, lane = tid & 63;
        #pragma unroll 1
        for (int r = 0; r < 4; ++r) {
            const int n = nb + wv * 4 + r;
            int m = cnt[n]; if (m > CAP) m = CAP;
            int val = (lane < m) ? lists[(long)n * CAP + lane] : 0x7FFFFFFF;
            #pragma unroll
            for (int k = 2; k <= 64; k <<= 1) {
                #pragma unroll
                for (int j = k >> 1; j > 0; j >>= 1) {
                    int other = __shfl_xor(val, j);
                    bool keepMin = (((lane & j) == 0) == ((lane & k) == 0));
                    int mn = val < other ? val : other;
                    int mx = val < other ? other : val;
                    val = keepMin ? mn : mx;
                }
            }
            lists[(long)n * CAP + lane] = val;
            if (lane == 0) { cnt[n] = m; degf[n] = (float)(m > 0 ? m : 1); }
        }
        __syncthreads();
    }
    const int ln = tid >> 4, jg = tid & 15;
    const int n = nb + ln;
    const int c0 = jg * 4;
    {   // gather: 16 threads/node, 4 feats each
        const int m = cnt[n];
        const int* l = lists + (long)n * CAP;
        const float inv = 1.0f / degf[n];
        float4 a = {0, 0, 0, 0};
        for (int e = 0; e < m; ++e) {
            float4 b = *reinterpret_cast<const float4*>(h + (long)l[e] * FEAT + c0);
            a.x += b.x; a.y += b.y; a.z += b.z; a.w += b.w;
        }
        float4 av = {a.x * inv, a.y * inv, a.z * inv, a.w * inv};
        *reinterpret_cast<float4*>(&v[ln][c0]) = av;
        *reinterpret_cast<float4*>(&v[ln][64 + c0]) =
            *reinterpret_cast<const float4*>(h + (long)n * FEAT + c0);
    }
    // ---- P1: rr = relu([aggr|h] @ Ws1 + bl1), K=128 in 2 chunks ----
    {
        float4 b0 = *reinterpret_cast<const float4*>(bl1 + c0);
        float4 b1 = *reinterpret_cast<const float4*>(bl1 + 64 + c0);
        float A0[4] = {b0.x, b0.y, b0.z, b0.w};
        float A1[4] = {b1.x, b1.y, b1.z, b1.w};
        for (int kc = 0; kc < 2; ++kc) {
            __syncthreads();                     // prev consumers done / v ready
            for (int e = tid; e < 2048; e += 256)
                *(reinterpret_cast<float4*>(wbuf) + e) =
                    *(reinterpret_cast<const float4*>(Ws1 + kc * 8192) + e);
            __syncthreads();
            #pragma unroll 4
            for (int k = 0; k < 64; ++k) {
                float a = v[ln][kc * 64 + k];
                float4 w0 = *reinterpret_cast<const float4*>(&wbuf[k * 128 + c0]);
                float4 w1 = *reinterpret_cast<const float4*>(&wbuf[k * 128 + 64 + c0]);
                A0[0] += a * w0.x; A0[1] += a * w0.y; A0[2] += a * w0.z; A0[3] += a * w0.w;
                A1[0] += a * w1.x; A1[1] += a * w1.y; A1[2] += a * w1.z; A1[3] += a * w1.w;
            }
        }
        float4 o0 = {fmaxf(A0[0],0.f), fmaxf(A0[1],0.f), fmaxf(A0[2],0.f), fmaxf(A0[3],0.f)};
        float4 o1 = {fmaxf(A1[0],0.f), fmaxf(A1[1],0.f), fmaxf(A1[2],0.f), fmaxf(A1[3],0.f)};
        *reinterpret_cast<float4*>(&rr[ln][c0]) = o0;
        *reinterpret_cast<float4*>(&rr[ln][64 + c0]) = o1;
    }
    // ---- P2: tt = relu(h @ Wf1 + bf1), K=64, one chunk ----
    {
        float4 b0 = *reinterpret_cast<const float4*>(bf1 + c0);
        float4 b1 = *reinterpret_cast<const float4*>(bf1 + 64 + c0);
        float A0[4] = {b0.x, b0.y, b0.z, b0.w};
        float A1[4] = {b1.x, b1.y, b1.z, b1.w};
        __syncthreads();
        for (int e = tid; e < 2048; e += 256)
            *(reinterpret_cast<float4*>(wbuf) + e) =
                *(reinterpret_cast<const float4*>(Wf1) + e);
        __syncthreads();
        #pragma unroll 4
        for (int k = 0; k < 64; ++k) {
            float a = v[ln][64 + k];
            float4 w0 = *reinterpret_cast<const float4*>(&wbuf[k * 128 + c0]);
            float4 w1 = *reinterpret_cast<const float4*>(&wbuf[k * 128 + 64 + c0]);
            A0[0] += a * w0.x; A0[1] += a * w0.y; A0[2] += a * w0.z; A0[3] += a * w0.w;
            A1[0] += a * w1.x; A1[1] += a * w1.y; A1[2] += a * w1.z; A1[3] += a * w1.w;
        }
        float4 o0 = {fmaxf(A0[0],0.f), fmaxf(A0[1],0.f), fmaxf(A0[2],0.f), fmaxf(A0[3],0.f)};
        float4 o1 = {fmaxf(A1[0],0.f), fmaxf(A1[1],0.f), fmaxf(A1[2],0.f), fmaxf(A1[3],0.f)};
        *reinterpret_cast<float4*>(&tt[ln][c0]) = o0;
        *reinterpret_cast<float4*>(&tt[ln][64 + c0]) = o1;
    }
    // ---- P3: xsl = tt @ Wf2 + bf2, K=128, 64 cols (Wf2 = [128][64]) ----
    {
        float4 b0 = *reinterpret_cast<const float4*>(bf2 + c0);
        float X[4] = {b0.x, b0.y, b0.z, b0.w};
        __syncthreads();
        for (int e = tid; e < 2048; e += 256)
            *(reinterpret_cast<float4*>(wbuf) + e) =
                *(reinterpret_cast<const float4*>(Wf2) + e);
        __syncthreads();
        #pragma unroll 4
        for (int k = 0; k < 128; ++k) {
            float a = tt[ln][k];
            float4 w = *reinterpret_cast<const float4*>(&wbuf[k * 64 + c0]);
            X[0] += a * w.x; X[1] += a * w.y; X[2] += a * w.z; X[3] += a * w.w;
        }
        float4 o = {X[0], X[1], X[2], X[3]};
        *reinterpret_cast<float4*>(&xsl[ln][c0]) = o;
    }
    // ---- P4: [pl|q] = rr @ Wc2 (+ bl2 + xsl on q half), K=128 in 2 chunks ----
    {
        float P0[4] = {0, 0, 0, 0};
        float P1[4] = {0, 0, 0, 0};
        for (int kc = 0; kc < 2; ++kc) {
            __syncthreads();
            for (int e = tid; e < 2048; e += 256)
                *(reinterpret_cast<float4*>(wbuf) + e) =
                    *(reinterpret_cast<const float4*>(Wc2 + kc * 8192) + e);
            __syncthreads();
            #pragma unroll 4
            for (int k = 0; k < 64; ++k) {
                float a = rr[ln][kc * 64 + k];
                float4 w0 = *reinterpret_cast<const float4*>(&wbuf[k * 128 + c0]);
                float4 w1 = *reinterpret_cast<const float4*>(&wbuf[k * 128 + 64 + c0]);
                P0[0] += a * w0.x; P0[1] += a * w0.y; P0[2] += a * w0.z; P0[3] += a * w0.w;
                P1[0] += a * w1.x; P1[1] += a * w1.y; P1[2] += a * w1.z; P1[3] += a * w1.w;
            }
        }
        float4 op = {P0[0], P0[1], P0[2], P0[3]};
        *reinterpret_cast<float4*>(pl + (long)n * FEAT + c0) = op;
        float4 bv = *reinterpret_cast<const float4*>(bl2 + c0);
        float4 oq = {P1[0] + bv.x + xsl[ln][c0 + 0],
                     P1[1] + bv.y + xsl[ln][c0 + 1],
                     P1[2] + bv.z + xsl[ln][c0 + 2],
                     P1[3] + bv.w + xsl[ln][c0 + 3]};
        *reinterpret_cast<float4*>(q + (long)n * FEAT + c0) = oq;
    }
}

// ---------------- gather + Euler epilogue (R12 verbatim) ----------------
__global__ __launch_bounds__(256)
void epi_kernel(const float* __restrict__ pl, const float* __restrict__ q,
                const int* __restrict__ lists, const int* __restrict__ cnt,
                const float* __restrict__ degf, const float* __restrict__ hcur,
                const float* __restrict__ tspan, int step,
                float* __restrict__ hnext) {
    const int tid = threadIdx.x;
    const int ln = tid >> 4, sub = tid & 15;
    const int n = blockIdx.x * 16 + ln;
    const int f0 = sub * 4;
    const int m = cnt[n];
    const int* l = lists + (long)n * CAP;
    const float inv = 1.0f / degf[n];
    float4 a = {0, 0, 0, 0};
    for (int e = 0; e < m; ++e) {
        float4 b = *reinterpret_cast<const float4*>(pl + (long)l[e] * FEAT + f0);
        a.x += b.x; a.y += b.y; a.z += b.z; a.w += b.w;
    }
    const float dt = tspan[step + 1] - tspan[step];
    float4 qv = *reinterpret_cast<const float4*>(q + (long)n * FEAT + f0);
    float4 hv = *reinterpret_cast<const float4*>(hcur + (long)n * FEAT + f0);
    float s0 = qv.x + a.x * inv, s1 = qv.y + a.y * inv;
    float s2 = qv.z + a.z * inv, s3 = qv.w + a.w * inv;
    s0 = fminf(fmaxf(s0, -1000.f), 1000.f); s1 = fminf(fmaxf(s1, -1000.f), 1000.f);
    s2 = fminf(fmaxf(s2, -1000.f), 1000.f); s3 = fminf(fmaxf(s3, -1000.f), 1000.f);
    float4 o = {hv.x + dt * s0, hv.y + dt * s1, hv.z + dt * s2, hv.w + dt * s3};
    *reinterpret_cast<float4*>(hnext + (long)n * FEAT + f0) = o;
}

extern "C" void kernel_launch(void* const* d_in, const int* in_sizes, int n_in,
                              void* d_out, int out_size, void* d_ws, size_t ws_size,
                              hipStream_t stream) {
    const float* tspan = (const float*)d_in[0];
    const float* x     = (const float*)d_in[1];
    const float* adj   = (const float*)d_in[2];
    const float* We1   = (const float*)d_in[3];
    const float* be1   = (const float*)d_in[4];
    const float* We2   = (const float*)d_in[5];
    const float* be2   = (const float*)d_in[6];
    const float* Wf1   = (const float*)d_in[7];
    const float* bf1   = (const float*)d_in[8];
    const float* Wf2   = (const float*)d_in[9];
    const float* bf2   = (const float*)d_in[10];
    const float* Wl1   = (const float*)d_in[11];
    const float* bl1   = (const float*)d_in[12];
    const float* Wr1   = (const float*)d_in[13];
    const float* Wl2   = (const float*)d_in[14];
    const float* bl2   = (const float*)d_in[15];
    const float* Wr2   = (const float*)d_in[16];
    float* out = (float*)d_out;

    // workspace layout (bytes)
    char* ws = (char*)d_ws;
    int*   lists = (int*)  (ws + 0);           // 8000*64*4  = 2,048,000
    int*   cnt   = (int*)  (ws + 2048000);     // 32,000
    float* degf  = (float*)(ws + 2080000);     // 32,000
    float* Ws1   = (float*)(ws + 2112000);     // 65,536
    float* Wc2   = (float*)(ws + 2177536);     // 65,536
    float* pl    = (float*)(ws + 2243072);     // 2,048,000
    float* q     = (float*)(ws + 4291072);     // 2,048,000
    // total 6,339,072 bytes

    zero_cnt_kernel<<<32, 256, 0, stream>>>(cnt);
    bis_kernel<<<2676, 256, 0, stream>>>(adj, cnt, lists, x, We1, be1, We2, be2,
                                         out, Wl1, Wr1, Wl2, Wr2, Ws1, Wc2);

    for (int s = 0; s < 3; ++s) {
        const float* hcur  = out + (long)s       * N_NODES * FEAT;
        float*       hnext = out + (long)(s + 1) * N_NODES * FEAT;
        sageproj_kernel<<<500, 256, 0, stream>>>(hcur, lists, cnt, degf, (s == 0) ? 1 : 0,
                                                 Ws1, bl1, Wc2, bl2,
                                                 Wf1, bf1, Wf2, bf2, pl, q);
        epi_kernel<<<500, 256, 0, stream>>>(pl, q, lists, cnt, degf, hcur, tspan, s, hnext);
    }
}

// Round 17
// 250.241 us; speedup vs baseline: 4.9283x; 1.1387x over previous
//
#include <hip/hip_runtime.h>

#define N_NODES 8000
#define FEAT 64
#define HID 128
#define LOOKBACK 12
#define CAP 64

// ---------------- zero the per-node counters ----------------
__global__ __launch_bounds__(256)
void zero_cnt_kernel(int* __restrict__ cnt) {
    int g = blockIdx.x * 256 + threadIdx.x;
    if (g < N_NODES) cnt[g] = 0;
}

// ---------------- adjacency extraction: 8-deep pipelined grid-stride ----------------
// R16 measured the old scan at 167us / ~1.5 TB/s: the load->waitcnt->branch chain
// keeps ONE 1KB load in flight per wave. Here each round issues 8 independent
// dwordx4 loads into registers (8KB/wave in flight) before any processing ->
// memory-level parallelism x8, scan should go HBM-bound (~45-60us).
// 2048 blocks x 256 threads = 524288 threads; 16M float4s = 30.5/thread:
// 3 rounds of 8 + 1 round of 6 + 1 guarded (t < 271360 does the 31st).
__global__ __launch_bounds__(256)
void build_adj_kernel(const float* __restrict__ adj, int* __restrict__ cnt,
                      int* __restrict__ lists) {
    const long NQ = (long)N_NODES * N_NODES / 4;     // 16,000,000
    const long STRIDE = 2048L * 256;                 // 524,288
    const long t = (long)blockIdx.x * 256 + threadIdx.x;

    auto proc = [&](float4 w, long q) {
        if (w.x != 0.0f || w.y != 0.0f || w.z != 0.0f || w.w != 0.0f) {
            int i  = (int)(q / (N_NODES / 4));
            int j0 = (int)(q % (N_NODES / 4)) * 4;
            float wv[4] = {w.x, w.y, w.z, w.w};
            #pragma unroll
            for (int c = 0; c < 4; ++c) {
                if (wv[c] != 0.0f) {
                    int j = j0 + c;
                    int p = atomicAdd(&cnt[j], 1);
                    if (p < CAP) lists[(long)j * CAP + p] = i;   // edge i -> j
                }
            }
        }
    };

    float4 w[8];
    #pragma unroll 1
    for (int r = 0; r < 3; ++r) {                    // iters 0..23, always in range
        const long base = t + (long)r * 8 * STRIDE;
        #pragma unroll
        for (int i = 0; i < 8; ++i)
            w[i] = *reinterpret_cast<const float4*>(adj + 4 * (base + (long)i * STRIDE));
        #pragma unroll
        for (int i = 0; i < 8; ++i)
            proc(w[i], base + (long)i * STRIDE);
    }
    {                                                // iters 24..29, always in range
        const long base = t + 24L * STRIDE;
        #pragma unroll
        for (int i = 0; i < 6; ++i)
            w[i] = *reinterpret_cast<const float4*>(adj + 4 * (base + (long)i * STRIDE));
        #pragma unroll
        for (int i = 0; i < 6; ++i)
            proc(w[i], base + (long)i * STRIDE);
    }
    {                                                // guarded iter 30
        const long q = t + 30L * STRIDE;
        if (q < NQ) proc(*reinterpret_cast<const float4*>(adj + 4 * q), q);
    }
}

// ---------------- canonicalize: wave-bitonic sort per node + deg + weights ----
__global__ __launch_bounds__(256)
void prep_kernel(int* __restrict__ cnt, int* __restrict__ lists,
                 float* __restrict__ degf,
                 const float* __restrict__ Wl1, const float* __restrict__ Wr1,
                 const float* __restrict__ Wl2, const float* __restrict__ Wr2,
                 float* __restrict__ Ws1, float* __restrict__ Wc2) {
    if (blockIdx.x < 2000) {
        const int wv   = threadIdx.x >> 6;
        const int lane = threadIdx.x & 63;
        const int n = blockIdx.x * 4 + wv;
        int m = cnt[n];
        if (m > CAP) m = CAP;
        int v = (lane < m) ? lists[(long)n * CAP + lane] : 0x7FFFFFFF;
        #pragma unroll
        for (int k = 2; k <= 64; k <<= 1) {
            #pragma unroll
            for (int j = k >> 1; j > 0; j >>= 1) {
                int other = __shfl_xor(v, j);
                bool keepMin = (((lane & j) == 0) == ((lane & k) == 0));
                int mn = v < other ? v : other;
                int mx = v < other ? other : v;
                v = keepMin ? mn : mx;
            }
        }
        lists[(long)n * CAP + lane] = v;
        if (lane == 0) {
            cnt[n]  = m;
            degf[n] = (float)(m > 0 ? m : 1);
        }
    } else {
        int u = (blockIdx.x - 2000) * 256 + threadIdx.x;
        if (u < 128 * 128) {            // Ws1[k][j] = [Wl1;Wr1] row-stacked
            int k = u >> 7, j = u & 127;
            Ws1[u] = (k < 64) ? Wl1[k * 128 + j] : Wr1[(k - 64) * 128 + j];
        } else if (u < 2 * 128 * 128) { // Wc2[k][j] = [Wl2 | Wr2] col-stacked
            int w = u - 128 * 128;
            int k = w >> 7, j = w & 127;
            Wc2[w] = (j < 64) ? Wl2[k * 64 + j] : Wr2[k * 64 + (j - 64)];
        }
    }
}

// ---------------- init encoder: x[L,N,F] -> x0[N,F], 4 elems/thread ----------------
__global__ __launch_bounds__(256)
void init_enc_kernel(const float* __restrict__ x, const float* __restrict__ We1,
                     const float* __restrict__ be1, const float* __restrict__ We2,
                     const float* __restrict__ be2, float* __restrict__ out0) {
    __shared__ float sW1T[HID * LOOKBACK];   // [h][l]
    __shared__ float sB1[HID];
    __shared__ float sW2[HID];
    for (int e = threadIdx.x; e < HID * LOOKBACK; e += 256) {
        int l = e / HID, h = e % HID;
        sW1T[h * LOOKBACK + l] = We1[e];
    }
    for (int e = threadIdx.x; e < HID; e += 256) { sB1[e] = be1[e]; sW2[e] = We2[e]; }
    __syncthreads();
    int g = (blockIdx.x * 256 + threadIdx.x) * 4;
    if (g >= N_NODES * FEAT) return;
    float xv[4][LOOKBACK];
    #pragma unroll
    for (int l = 0; l < LOOKBACK; ++l) {
        float4 v = *reinterpret_cast<const float4*>(x + (long)l * N_NODES * FEAT + g);
        xv[0][l] = v.x; xv[1][l] = v.y; xv[2][l] = v.z; xv[3][l] = v.w;
    }
    float b2 = be2[0];
    float acc[4] = {b2, b2, b2, b2};
    for (int h = 0; h < HID; ++h) {
        float s0 = sB1[h], s1 = s0, s2 = s0, s3 = s0;
        #pragma unroll
        for (int l = 0; l < LOOKBACK; ++l) {
            float w = sW1T[h * LOOKBACK + l];
            s0 += xv[0][l] * w; s1 += xv[1][l] * w;
            s2 += xv[2][l] * w; s3 += xv[3][l] * w;
        }
        float w2 = sW2[h];
        acc[0] += fmaxf(s0, 0.0f) * w2; acc[1] += fmaxf(s1, 0.0f) * w2;
        acc[2] += fmaxf(s2, 0.0f) * w2; acc[3] += fmaxf(s3, 0.0f) * w2;
    }
    float4 o = {acc[0], acc[1], acc[2], acc[3]};
    *reinterpret_cast<float4*>(out0 + g) = o;
}

// ---------------- fused SAGE1 + proj + selfMLP (R12 verbatim) ----------------
__global__ __launch_bounds__(256)
void sageproj_kernel(const float* __restrict__ h, const int* __restrict__ lists,
                     const int* __restrict__ cnt, const float* __restrict__ degf,
                     const float* __restrict__ Ws1, const float* __restrict__ bl1,
                     const float* __restrict__ Wc2, const float* __restrict__ bl2,
                     const float* __restrict__ Wf1, const float* __restrict__ bf1,
                     const float* __restrict__ Wf2, const float* __restrict__ bf2,
                     float* __restrict__ pl, float* __restrict__ q) {
    __shared__ float v[16][132];     // [node][k]: k<64 aggr, k>=64 h row
    __shared__ float rr[16][132];    // r1
    __shared__ float tt[16][132];    // t = relu(h@Wf1+bf1)
    __shared__ float xsl[16][68];    // xs
    __shared__ float wbuf[64 * 128]; // 32 KB weight panel chunk
    const int tid = threadIdx.x;
    const int nb = blockIdx.x * 16;
    const int ln = tid >> 4, jg = tid & 15;
    const int n = nb + ln;
    const int c0 = jg * 4;
    {   // gather: 16 threads/node, 4 feats each
        const int m = cnt[n];
        const int* l = lists + (long)n * CAP;
        const float inv = 1.0f / degf[n];
        float4 a = {0, 0, 0, 0};
        for (int e = 0; e < m; ++e) {
            float4 b = *reinterpret_cast<const float4*>(h + (long)l[e] * FEAT + c0);
            a.x += b.x; a.y += b.y; a.z += b.z; a.w += b.w;
        }
        float4 av = {a.x * inv, a.y * inv, a.z * inv, a.w * inv};
        *reinterpret_cast<float4*>(&v[ln][c0]) = av;
        *reinterpret_cast<float4*>(&v[ln][64 + c0]) =
            *reinterpret_cast<const float4*>(h + (long)n * FEAT + c0);
    }
    // ---- P1: rr = relu([aggr|h] @ Ws1 + bl1), K=128 in 2 chunks ----
    {
        float4 b0 = *reinterpret_cast<const float4*>(bl1 + c0);
        float4 b1 = *reinterpret_cast<const float4*>(bl1 + 64 + c0);
        float A0[4] = {b0.x, b0.y, b0.z, b0.w};
        float A1[4] = {b1.x, b1.y, b1.z, b1.w};
        for (int kc = 0; kc < 2; ++kc) {
            __syncthreads();                     // prev consumers done / v ready
            for (int e = tid; e < 2048; e += 256)
                *(reinterpret_cast<float4*>(wbuf) + e) =
                    *(reinterpret_cast<const float4*>(Ws1 + kc * 8192) + e);
            __syncthreads();
            #pragma unroll 4
            for (int k = 0; k < 64; ++k) {
                float a = v[ln][kc * 64 + k];
                float4 w0 = *reinterpret_cast<const float4*>(&wbuf[k * 128 + c0]);
                float4 w1 = *reinterpret_cast<const float4*>(&wbuf[k * 128 + 64 + c0]);
                A0[0] += a * w0.x; A0[1] += a * w0.y; A0[2] += a * w0.z; A0[3] += a * w0.w;
                A1[0] += a * w1.x; A1[1] += a * w1.y; A1[2] += a * w1.z; A1[3] += a * w1.w;
            }
        }
        float4 o0 = {fmaxf(A0[0],0.f), fmaxf(A0[1],0.f), fmaxf(A0[2],0.f), fmaxf(A0[3],0.f)};
        float4 o1 = {fmaxf(A1[0],0.f), fmaxf(A1[1],0.f), fmaxf(A1[2],0.f), fmaxf(A1[3],0.f)};
        *reinterpret_cast<float4*>(&rr[ln][c0]) = o0;
        *reinterpret_cast<float4*>(&rr[ln][64 + c0]) = o1;
    }
    // ---- P2: tt = relu(h @ Wf1 + bf1), K=64, one chunk ----
    {
        float4 b0 = *reinterpret_cast<const float4*>(bf1 + c0);
        float4 b1 = *reinterpret_cast<const float4*>(bf1 + 64 + c0);
        float A0[4] = {b0.x, b0.y, b0.z, b0.w};
        float A1[4] = {b1.x, b1.y, b1.z, b1.w};
        __syncthreads();
        for (int e = tid; e < 2048; e += 256)
            *(reinterpret_cast<float4*>(wbuf) + e) =
                *(reinterpret_cast<const float4*>(Wf1) + e);
        __syncthreads();
        #pragma unroll 4
        for (int k = 0; k < 64; ++k) {
            float a = v[ln][64 + k];
            float4 w0 = *reinterpret_cast<const float4*>(&wbuf[k * 128 + c0]);
            float4 w1 = *reinterpret_cast<const float4*>(&wbuf[k * 128 + 64 + c0]);
            A0[0] += a * w0.x; A0[1] += a * w0.y; A0[2] += a * w0.z; A0[3] += a * w0.w;
            A1[0] += a * w1.x; A1[1] += a * w1.y; A1[2] += a * w1.z; A1[3] += a * w1.w;
        }
        float4 o0 = {fmaxf(A0[0],0.f), fmaxf(A0[1],0.f), fmaxf(A0[2],0.f), fmaxf(A0[3],0.f)};
        float4 o1 = {fmaxf(A1[0],0.f), fmaxf(A1[1],0.f), fmaxf(A1[2],0.f), fmaxf(A1[3],0.f)};
        *reinterpret_cast<float4*>(&tt[ln][c0]) = o0;
        *reinterpret_cast<float4*>(&tt[ln][64 + c0]) = o1;
    }
    // ---- P3: xsl = tt @ Wf2 + bf2, K=128, 64 cols, one chunk (Wf2 = [128][64]) ----
    {
        float4 b0 = *reinterpret_cast<const float4*>(bf2 + c0);
        float X[4] = {b0.x, b0.y, b0.z, b0.w};
        __syncthreads();
        for (int e = tid; e < 2048; e += 256)
            *(reinterpret_cast<float4*>(wbuf) + e) =
                *(reinterpret_cast<const float4*>(Wf2) + e);
        __syncthreads();
        #pragma unroll 4
        for (int k = 0; k < 128; ++k) {
            float a = tt[ln][k];
            float4 w = *reinterpret_cast<const float4*>(&wbuf[k * 64 + c0]);
            X[0] += a * w.x; X[1] += a * w.y; X[2] += a * w.z; X[3] += a * w.w;
        }
        float4 o = {X[0], X[1], X[2], X[3]};
        *reinterpret_cast<float4*>(&xsl[ln][c0]) = o;
    }
    // ---- P4: [pl|q] = rr @ Wc2 (+ bl2 + xsl on q half), K=128 in 2 chunks ----
    {
        float P0[4] = {0, 0, 0, 0};
        float P1[4] = {0, 0, 0, 0};
        for (int kc = 0; kc < 2; ++kc) {
            __syncthreads();
            for (int e = tid; e < 2048; e += 256)
                *(reinterpret_cast<float4*>(wbuf) + e) =
                    *(reinterpret_cast<const float4*>(Wc2 + kc * 8192) + e);
            __syncthreads();
            #pragma unroll 4
            for (int k = 0; k < 64; ++k) {
                float a = rr[ln][kc * 64 + k];
                float4 w0 = *reinterpret_cast<const float4*>(&wbuf[k * 128 + c0]);
                float4 w1 = *reinterpret_cast<const float4*>(&wbuf[k * 128 + 64 + c0]);
                P0[0] += a * w0.x; P0[1] += a * w0.y; P0[2] += a * w0.z; P0[3] += a * w0.w;
                P1[0] += a * w1.x; P1[1] += a * w1.y; P1[2] += a * w1.z; P1[3] += a * w1.w;
            }
        }
        float4 op = {P0[0], P0[1], P0[2], P0[3]};
        *reinterpret_cast<float4*>(pl + (long)n * FEAT + c0) = op;
        float4 bv = *reinterpret_cast<const float4*>(bl2 + c0);
        float4 oq = {P1[0] + bv.x + xsl[ln][c0 + 0],
                     P1[1] + bv.y + xsl[ln][c0 + 1],
                     P1[2] + bv.z + xsl[ln][c0 + 2],
                     P1[3] + bv.w + xsl[ln][c0 + 3]};
        *reinterpret_cast<float4*>(q + (long)n * FEAT + c0) = oq;
    }
}

// ---------------- gather + Euler epilogue (R12 verbatim) ----------------
__global__ __launch_bounds__(256)
void epi_kernel(const float* __restrict__ pl, const float* __restrict__ q,
                const int* __restrict__ lists, const int* __restrict__ cnt,
                const float* __restrict__ degf, const float* __restrict__ hcur,
                const float* __restrict__ tspan, int step,
                float* __restrict__ hnext) {
    const int tid = threadIdx.x;
    const int ln = tid >> 4, sub = tid & 15;
    const int n = blockIdx.x * 16 + ln;
    const int f0 = sub * 4;
    const int m = cnt[n];
    const int* l = lists + (long)n * CAP;
    const float inv = 1.0f / degf[n];
    float4 a = {0, 0, 0, 0};
    for (int e = 0; e < m; ++e) {
        float4 b = *reinterpret_cast<const float4*>(pl + (long)l[e] * FEAT + f0);
        a.x += b.x; a.y += b.y; a.z += b.z; a.w += b.w;
    }
    const float dt = tspan[step + 1] - tspan[step];
    float4 qv = *reinterpret_cast<const float4*>(q + (long)n * FEAT + f0);
    float4 hv = *reinterpret_cast<const float4*>(hcur + (long)n * FEAT + f0);
    float s0 = qv.x + a.x * inv, s1 = qv.y + a.y * inv;
    float s2 = qv.z + a.z * inv, s3 = qv.w + a.w * inv;
    s0 = fminf(fmaxf(s0, -1000.f), 1000.f); s1 = fminf(fmaxf(s1, -1000.f), 1000.f);
    s2 = fminf(fmaxf(s2, -1000.f), 1000.f); s3 = fminf(fmaxf(s3, -1000.f), 1000.f);
    float4 o = {hv.x + dt * s0, hv.y + dt * s1, hv.z + dt * s2, hv.w + dt * s3};
    *reinterpret_cast<float4*>(hnext + (long)n * FEAT + f0) = o;
}

extern "C" void kernel_launch(void* const* d_in, const int* in_sizes, int n_in,
                              void* d_out, int out_size, void* d_ws, size_t ws_size,
                              hipStream_t stream) {
    const float* tspan = (const float*)d_in[0];
    const float* x     = (const float*)d_in[1];
    const float* adj   = (const float*)d_in[2];
    const float* We1   = (const float*)d_in[3];
    const float* be1   = (const float*)d_in[4];
    const float* We2   = (const float*)d_in[5];
    const float* be2   = (const float*)d_in[6];
    const float* Wf1   = (const float*)d_in[7];
    const float* bf1   = (const float*)d_in[8];
    const float* Wf2   = (const float*)d_in[9];
    const float* bf2   = (const float*)d_in[10];
    const float* Wl1   = (const float*)d_in[11];
    const float* bl1   = (const float*)d_in[12];
    const float* Wr1   = (const float*)d_in[13];
    const float* Wl2   = (const float*)d_in[14];
    const float* bl2   = (const float*)d_in[15];
    const float* Wr2   = (const float*)d_in[16];
    float* out = (float*)d_out;

    // workspace layout (bytes)
    char* ws = (char*)d_ws;
    int*   lists = (int*)  (ws + 0);           // 8000*64*4  = 2,048,000
    int*   cnt   = (int*)  (ws + 2048000);     // 32,000
    float* degf  = (float*)(ws + 2080000);     // 32,000
    float* Ws1   = (float*)(ws + 2112000);     // 65,536
    float* Wc2   = (float*)(ws + 2177536);     // 65,536
    float* pl    = (float*)(ws + 2243072);     // 2,048,000
    float* q     = (float*)(ws + 4291072);     // 2,048,000
    // total 6,339,072 bytes

    zero_cnt_kernel<<<32, 256, 0, stream>>>(cnt);
    build_adj_kernel<<<2048, 256, 0, stream>>>(adj, cnt, lists);
    prep_kernel<<<2128, 256, 0, stream>>>(cnt, lists, degf, Wl1, Wr1, Wl2, Wr2, Ws1, Wc2);
    init_enc_kernel<<<500, 256, 0, stream>>>(x, We1, be1, We2, be2, out);

    for (int s = 0; s < 3; ++s) {
        const float* hcur  = out + (long)s       * N_NODES * FEAT;
        float*       hnext = out + (long)(s + 1) * N_NODES * FEAT;
        sageproj_kernel<<<500, 256, 0, stream>>>(hcur, lists, cnt, degf,
                                                 Ws1, bl1, Wc2, bl2,
                                                 Wf1, bf1, Wf2, bf2, pl, q);
        epi_kernel<<<500, 256, 0, stream>>>(pl, q, lists, cnt, degf, hcur, tspan, s, hnext);
    }
}

// Round 18
// 246.057 us; speedup vs baseline: 5.0120x; 1.0170x over previous
//
#include <hip/hip_runtime.h>

#define N_NODES 8000
#define FEAT 64
#define HID 128
#define LOOKBACK 12
#define CAP 64

// ---------------- zero the per-node counters ----------------
__global__ __launch_bounds__(256)
void zero_cnt_kernel(int* __restrict__ cnt) {
    int g = blockIdx.x * 256 + threadIdx.x;
    if (g < N_NODES) cnt[g] = 0;
}

// ---------------- adjacency extraction: stream-then-drain ----------------
// R16/R17 diagnosis: the old scan was ATOMIC-LATENCY-bound (dependent
// atomicAdd->store chain ~1200cy inside the scan loop; VALUBusy 22-31%).
// Phase 1 streams all 256MB with NO memory ops in the body: hits are packed
// into 10 named registers (lambda~0.24/thread, P(overflow)~3e-9).
// Phase 2 drains <=10 INDEPENDENT atomic+store chains back-to-back -> they
// overlap instead of serializing with the stream. Append order is arbitrary;
// prep's bitonic sort canonicalizes -> bit-identical downstream.
__global__ __launch_bounds__(256)
void build_adj_kernel(const float* __restrict__ adj, int* __restrict__ cnt,
                      int* __restrict__ lists) {
    const long NQ = (long)N_NODES * N_NODES / 4;     // 16,000,000 float4s
    const long STRIDE = 2048L * 256;                 // 524,288 threads
    const long t = (long)blockIdx.x * 256 + threadIdx.x;

    int lc = 0;
    int e0 = 0, e1 = 0, e2 = 0, e3 = 0, e4 = 0;
    int e5 = 0, e6 = 0, e7 = 0, e8 = 0, e9 = 0;

    #pragma unroll 1
    for (long q = t; q < NQ; q += STRIDE) {
        float4 w = *reinterpret_cast<const float4*>(adj + 4 * q);
        if (w.x != 0.0f || w.y != 0.0f || w.z != 0.0f || w.w != 0.0f) {
            float wv[4] = {w.x, w.y, w.z, w.w};
            #pragma unroll
            for (int c = 0; c < 4; ++c) {
                if (wv[c] != 0.0f) {
                    int e = (int)(q * 4 + c);        // linear elem idx = i*8000+j
                    if      (lc == 0) e0 = e;
                    else if (lc == 1) e1 = e;
                    else if (lc == 2) e2 = e;
                    else if (lc == 3) e3 = e;
                    else if (lc == 4) e4 = e;
                    else if (lc == 5) e5 = e;
                    else if (lc == 6) e6 = e;
                    else if (lc == 7) e7 = e;
                    else if (lc == 8) e8 = e;
                    else if (lc == 9) e9 = e;
                    ++lc;
                }
            }
        }
    }
    // drain: independent atomic+store chains (overlapping)
    #define DRAIN(K, EK)                                                     \
        if (lc > K) {                                                        \
            int ii = (EK) / N_NODES;                                         \
            int jj = (EK) % N_NODES;                                         \
            int p = atomicAdd(&cnt[jj], 1);                                  \
            if (p < CAP) lists[(long)jj * CAP + p] = ii;                     \
        }
    DRAIN(0, e0) DRAIN(1, e1) DRAIN(2, e2) DRAIN(3, e3) DRAIN(4, e4)
    DRAIN(5, e5) DRAIN(6, e6) DRAIN(7, e7) DRAIN(8, e8) DRAIN(9, e9)
    #undef DRAIN
}

// ---------------- canonicalize: wave-bitonic sort per node + deg + weights ----
__global__ __launch_bounds__(256)
void prep_kernel(int* __restrict__ cnt, int* __restrict__ lists,
                 float* __restrict__ degf,
                 const float* __restrict__ Wl1, const float* __restrict__ Wr1,
                 const float* __restrict__ Wl2, const float* __restrict__ Wr2,
                 float* __restrict__ Ws1, float* __restrict__ Wc2) {
    if (blockIdx.x < 2000) {
        const int wv   = threadIdx.x >> 6;
        const int lane = threadIdx.x & 63;
        const int n = blockIdx.x * 4 + wv;
        int m = cnt[n];
        if (m > CAP) m = CAP;
        int v = (lane < m) ? lists[(long)n * CAP + lane] : 0x7FFFFFFF;
        #pragma unroll
        for (int k = 2; k <= 64; k <<= 1) {
            #pragma unroll
            for (int j = k >> 1; j > 0; j >>= 1) {
                int other = __shfl_xor(v, j);
                bool keepMin = (((lane & j) == 0) == ((lane & k) == 0));
                int mn = v < other ? v : other;
                int mx = v < other ? other : v;
                v = keepMin ? mn : mx;
            }
        }
        lists[(long)n * CAP + lane] = v;
        if (lane == 0) {
            cnt[n]  = m;
            degf[n] = (float)(m > 0 ? m : 1);
        }
    } else {
        int u = (blockIdx.x - 2000) * 256 + threadIdx.x;
        if (u < 128 * 128) {            // Ws1[k][j] = [Wl1;Wr1] row-stacked
            int k = u >> 7, j = u & 127;
            Ws1[u] = (k < 64) ? Wl1[k * 128 + j] : Wr1[(k - 64) * 128 + j];
        } else if (u < 2 * 128 * 128) { // Wc2[k][j] = [Wl2 | Wr2] col-stacked
            int w = u - 128 * 128;
            int k = w >> 7, j = w & 127;
            Wc2[w] = (j < 64) ? Wl2[k * 64 + j] : Wr2[k * 64 + (j - 64)];
        }
    }
}

// ---------------- init encoder: x[L,N,F] -> x0[N,F], 4 elems/thread ----------------
__global__ __launch_bounds__(256)
void init_enc_kernel(const float* __restrict__ x, const float* __restrict__ We1,
                     const float* __restrict__ be1, const float* __restrict__ We2,
                     const float* __restrict__ be2, float* __restrict__ out0) {
    __shared__ float sW1T[HID * LOOKBACK];   // [h][l]
    __shared__ float sB1[HID];
    __shared__ float sW2[HID];
    for (int e = threadIdx.x; e < HID * LOOKBACK; e += 256) {
        int l = e / HID, h = e % HID;
        sW1T[h * LOOKBACK + l] = We1[e];
    }
    for (int e = threadIdx.x; e < HID; e += 256) { sB1[e] = be1[e]; sW2[e] = We2[e]; }
    __syncthreads();
    int g = (blockIdx.x * 256 + threadIdx.x) * 4;
    if (g >= N_NODES * FEAT) return;
    float xv[4][LOOKBACK];
    #pragma unroll
    for (int l = 0; l < LOOKBACK; ++l) {
        float4 v = *reinterpret_cast<const float4*>(x + (long)l * N_NODES * FEAT + g);
        xv[0][l] = v.x; xv[1][l] = v.y; xv[2][l] = v.z; xv[3][l] = v.w;
    }
    float b2 = be2[0];
    float acc[4] = {b2, b2, b2, b2};
    for (int h = 0; h < HID; ++h) {
        float s0 = sB1[h], s1 = s0, s2 = s0, s3 = s0;
        #pragma unroll
        for (int l = 0; l < LOOKBACK; ++l) {
            float w = sW1T[h * LOOKBACK + l];
            s0 += xv[0][l] * w; s1 += xv[1][l] * w;
            s2 += xv[2][l] * w; s3 += xv[3][l] * w;
        }
        float w2 = sW2[h];
        acc[0] += fmaxf(s0, 0.0f) * w2; acc[1] += fmaxf(s1, 0.0f) * w2;
        acc[2] += fmaxf(s2, 0.0f) * w2; acc[3] += fmaxf(s3, 0.0f) * w2;
    }
    float4 o = {acc[0], acc[1], acc[2], acc[3]};
    *reinterpret_cast<float4*>(out0 + g) = o;
}

// ---------------- fused SAGE1 + proj + selfMLP (R12 verbatim) ----------------
__global__ __launch_bounds__(256)
void sageproj_kernel(const float* __restrict__ h, const int* __restrict__ lists,
                     const int* __restrict__ cnt, const float* __restrict__ degf,
                     const float* __restrict__ Ws1, const float* __restrict__ bl1,
                     const float* __restrict__ Wc2, const float* __restrict__ bl2,
                     const float* __restrict__ Wf1, const float* __restrict__ bf1,
                     const float* __restrict__ Wf2, const float* __restrict__ bf2,
                     float* __restrict__ pl, float* __restrict__ q) {
    __shared__ float v[16][132];     // [node][k]: k<64 aggr, k>=64 h row
    __shared__ float rr[16][132];    // r1
    __shared__ float tt[16][132];    // t = relu(h@Wf1+bf1)
    __shared__ float xsl[16][68];    // xs
    __shared__ float wbuf[64 * 128]; // 32 KB weight panel chunk
    const int tid = threadIdx.x;
    const int nb = blockIdx.x * 16;
    const int ln = tid >> 4, jg = tid & 15;
    const int n = nb + ln;
    const int c0 = jg * 4;
    {   // gather: 16 threads/node, 4 feats each
        const int m = cnt[n];
        const int* l = lists + (long)n * CAP;
        const float inv = 1.0f / degf[n];
        float4 a = {0, 0, 0, 0};
        for (int e = 0; e < m; ++e) {
            float4 b = *reinterpret_cast<const float4*>(h + (long)l[e] * FEAT + c0);
            a.x += b.x; a.y += b.y; a.z += b.z; a.w += b.w;
        }
        float4 av = {a.x * inv, a.y * inv, a.z * inv, a.w * inv};
        *reinterpret_cast<float4*>(&v[ln][c0]) = av;
        *reinterpret_cast<float4*>(&v[ln][64 + c0]) =
            *reinterpret_cast<const float4*>(h + (long)n * FEAT + c0);
    }
    // ---- P1: rr = relu([aggr|h] @ Ws1 + bl1), K=128 in 2 chunks ----
    {
        float4 b0 = *reinterpret_cast<const float4*>(bl1 + c0);
        float4 b1 = *reinterpret_cast<const float4*>(bl1 + 64 + c0);
        float A0[4] = {b0.x, b0.y, b0.z, b0.w};
        float A1[4] = {b1.x, b1.y, b1.z, b1.w};
        for (int kc = 0; kc < 2; ++kc) {
            __syncthreads();                     // prev consumers done / v ready
            for (int e = tid; e < 2048; e += 256)
                *(reinterpret_cast<float4*>(wbuf) + e) =
                    *(reinterpret_cast<const float4*>(Ws1 + kc * 8192) + e);
            __syncthreads();
            #pragma unroll 4
            for (int k = 0; k < 64; ++k) {
                float a = v[ln][kc * 64 + k];
                float4 w0 = *reinterpret_cast<const float4*>(&wbuf[k * 128 + c0]);
                float4 w1 = *reinterpret_cast<const float4*>(&wbuf[k * 128 + 64 + c0]);
                A0[0] += a * w0.x; A0[1] += a * w0.y; A0[2] += a * w0.z; A0[3] += a * w0.w;
                A1[0] += a * w1.x; A1[1] += a * w1.y; A1[2] += a * w1.z; A1[3] += a * w1.w;
            }
        }
        float4 o0 = {fmaxf(A0[0],0.f), fmaxf(A0[1],0.f), fmaxf(A0[2],0.f), fmaxf(A0[3],0.f)};
        float4 o1 = {fmaxf(A1[0],0.f), fmaxf(A1[1],0.f), fmaxf(A1[2],0.f), fmaxf(A1[3],0.f)};
        *reinterpret_cast<float4*>(&rr[ln][c0]) = o0;
        *reinterpret_cast<float4*>(&rr[ln][64 + c0]) = o1;
    }
    // ---- P2: tt = relu(h @ Wf1 + bf1), K=64, one chunk ----
    {
        float4 b0 = *reinterpret_cast<const float4*>(bf1 + c0);
        float4 b1 = *reinterpret_cast<const float4*>(bf1 + 64 + c0);
        float A0[4] = {b0.x, b0.y, b0.z, b0.w};
        float A1[4] = {b1.x, b1.y, b1.z, b1.w};
        __syncthreads();
        for (int e = tid; e < 2048; e += 256)
            *(reinterpret_cast<float4*>(wbuf) + e) =
                *(reinterpret_cast<const float4*>(Wf1) + e);
        __syncthreads();
        #pragma unroll 4
        for (int k = 0; k < 64; ++k) {
            float a = v[ln][64 + k];
            float4 w0 = *reinterpret_cast<const float4*>(&wbuf[k * 128 + c0]);
            float4 w1 = *reinterpret_cast<const float4*>(&wbuf[k * 128 + 64 + c0]);
            A0[0] += a * w0.x; A0[1] += a * w0.y; A0[2] += a * w0.z; A0[3] += a * w0.w;
            A1[0] += a * w1.x; A1[1] += a * w1.y; A1[2] += a * w1.z; A1[3] += a * w1.w;
        }
        float4 o0 = {fmaxf(A0[0],0.f), fmaxf(A0[1],0.f), fmaxf(A0[2],0.f), fmaxf(A0[3],0.f)};
        float4 o1 = {fmaxf(A1[0],0.f), fmaxf(A1[1],0.f), fmaxf(A1[2],0.f), fmaxf(A1[3],0.f)};
        *reinterpret_cast<float4*>(&tt[ln][c0]) = o0;
        *reinterpret_cast<float4*>(&tt[ln][64 + c0]) = o1;
    }
    // ---- P3: xsl = tt @ Wf2 + bf2, K=128, 64 cols, one chunk (Wf2 = [128][64]) ----
    {
        float4 b0 = *reinterpret_cast<const float4*>(bf2 + c0);
        float X[4] = {b0.x, b0.y, b0.z, b0.w};
        __syncthreads();
        for (int e = tid; e < 2048; e += 256)
            *(reinterpret_cast<float4*>(wbuf) + e) =
                *(reinterpret_cast<const float4*>(Wf2) + e);
        __syncthreads();
        #pragma unroll 4
        for (int k = 0; k < 128; ++k) {
            float a = tt[ln][k];
            float4 w = *reinterpret_cast<const float4*>(&wbuf[k * 64 + c0]);
            X[0] += a * w.x; X[1] += a * w.y; X[2] += a * w.z; X[3] += a * w.w;
        }
        float4 o = {X[0], X[1], X[2], X[3]};
        *reinterpret_cast<float4*>(&xsl[ln][c0]) = o;
    }
    // ---- P4: [pl|q] = rr @ Wc2 (+ bl2 + xsl on q half), K=128 in 2 chunks ----
    {
        float P0[4] = {0, 0, 0, 0};
        float P1[4] = {0, 0, 0, 0};
        for (int kc = 0; kc < 2; ++kc) {
            __syncthreads();
            for (int e = tid; e < 2048; e += 256)
                *(reinterpret_cast<float4*>(wbuf) + e) =
                    *(reinterpret_cast<const float4*>(Wc2 + kc * 8192) + e);
            __syncthreads();
            #pragma unroll 4
            for (int k = 0; k < 64; ++k) {
                float a = rr[ln][kc * 64 + k];
                float4 w0 = *reinterpret_cast<const float4*>(&wbuf[k * 128 + c0]);
                float4 w1 = *reinterpret_cast<const float4*>(&wbuf[k * 128 + 64 + c0]);
                P0[0] += a * w0.x; P0[1] += a * w0.y; P0[2] += a * w0.z; P0[3] += a * w0.w;
                P1[0] += a * w1.x; P1[1] += a * w1.y; P1[2] += a * w1.z; P1[3] += a * w1.w;
            }
        }
        float4 op = {P0[0], P0[1], P0[2], P0[3]};
        *reinterpret_cast<float4*>(pl + (long)n * FEAT + c0) = op;
        float4 bv = *reinterpret_cast<const float4*>(bl2 + c0);
        float4 oq = {P1[0] + bv.x + xsl[ln][c0 + 0],
                     P1[1] + bv.y + xsl[ln][c0 + 1],
                     P1[2] + bv.z + xsl[ln][c0 + 2],
                     P1[3] + bv.w + xsl[ln][c0 + 3]};
        *reinterpret_cast<float4*>(q + (long)n * FEAT + c0) = oq;
    }
}

// ---------------- gather + Euler epilogue (R12 verbatim) ----------------
__global__ __launch_bounds__(256)
void epi_kernel(const float* __restrict__ pl, const float* __restrict__ q,
                const int* __restrict__ lists, const int* __restrict__ cnt,
                const float* __restrict__ degf, const float* __restrict__ hcur,
                const float* __restrict__ tspan, int step,
                float* __restrict__ hnext) {
    const int tid = threadIdx.x;
    const int ln = tid >> 4, sub = tid & 15;
    const int n = blockIdx.x * 16 + ln;
    const int f0 = sub * 4;
    const int m = cnt[n];
    const int* l = lists + (long)n * CAP;
    const float inv = 1.0f / degf[n];
    float4 a = {0, 0, 0, 0};
    for (int e = 0; e < m; ++e) {
        float4 b = *reinterpret_cast<const float4*>(pl + (long)l[e] * FEAT + f0);
        a.x += b.x; a.y += b.y; a.z += b.z; a.w += b.w;
    }
    const float dt = tspan[step + 1] - tspan[step];
    float4 qv = *reinterpret_cast<const float4*>(q + (long)n * FEAT + f0);
    float4 hv = *reinterpret_cast<const float4*>(hcur + (long)n * FEAT + f0);
    float s0 = qv.x + a.x * inv, s1 = qv.y + a.y * inv;
    float s2 = qv.z + a.z * inv, s3 = qv.w + a.w * inv;
    s0 = fminf(fmaxf(s0, -1000.f), 1000.f); s1 = fminf(fmaxf(s1, -1000.f), 1000.f);
    s2 = fminf(fmaxf(s2, -1000.f), 1000.f); s3 = fminf(fmaxf(s3, -1000.f), 1000.f);
    float4 o = {hv.x + dt * s0, hv.y + dt * s1, hv.z + dt * s2, hv.w + dt * s3};
    *reinterpret_cast<float4*>(hnext + (long)n * FEAT + f0) = o;
}

extern "C" void kernel_launch(void* const* d_in, const int* in_sizes, int n_in,
                              void* d_out, int out_size, void* d_ws, size_t ws_size,
                              hipStream_t stream) {
    const float* tspan = (const float*)d_in[0];
    const float* x     = (const float*)d_in[1];
    const float* adj   = (const float*)d_in[2];
    const float* We1   = (const float*)d_in[3];
    const float* be1   = (const float*)d_in[4];
    const float* We2   = (const float*)d_in[5];
    const float* be2   = (const float*)d_in[6];
    const float* Wf1   = (const float*)d_in[7];
    const float* bf1   = (const float*)d_in[8];
    const float* Wf2   = (const float*)d_in[9];
    const float* bf2   = (const float*)d_in[10];
    const float* Wl1   = (const float*)d_in[11];
    const float* bl1   = (const float*)d_in[12];
    const float* Wr1   = (const float*)d_in[13];
    const float* Wl2   = (const float*)d_in[14];
    const float* bl2   = (const float*)d_in[15];
    const float* Wr2   = (const float*)d_in[16];
    float* out = (float*)d_out;

    // workspace layout (bytes)
    char* ws = (char*)d_ws;
    int*   lists = (int*)  (ws + 0);           // 8000*64*4  = 2,048,000
    int*   cnt   = (int*)  (ws + 2048000);     // 32,000
    float* degf  = (float*)(ws + 2080000);     // 32,000
    float* Ws1   = (float*)(ws + 2112000);     // 65,536
    float* Wc2   = (float*)(ws + 2177536);     // 65,536
    float* pl    = (float*)(ws + 2243072);     // 2,048,000
    float* q     = (float*)(ws + 4291072);     // 2,048,000
    // total 6,339,072 bytes

    zero_cnt_kernel<<<32, 256, 0, stream>>>(cnt);
    build_adj_kernel<<<2048, 256, 0, stream>>>(adj, cnt, lists);
    prep_kernel<<<2128, 256, 0, stream>>>(cnt, lists, degf, Wl1, Wr1, Wl2, Wr2, Ws1, Wc2);
    init_enc_kernel<<<500, 256, 0, stream>>>(x, We1, be1, We2, be2, out);

    for (int s = 0; s < 3; ++s) {
        const float* hcur  = out + (long)s       * N_NODES * FEAT;
        float*       hnext = out + (long)(s + 1) * N_NODES * FEAT;
        sageproj_kernel<<<500, 256, 0, stream>>>(hcur, lists, cnt, degf,
                                                 Ws1, bl1, Wc2, bl2,
                                                 Wf1, bf1, Wf2, bf2, pl, q);
        epi_kernel<<<500, 256, 0, stream>>>(pl, q, lists, cnt, degf, hcur, tspan, s, hnext);
    }
}

// Round 19
// 242.097 us; speedup vs baseline: 5.0940x; 1.0164x over previous
//
#include <hip/hip_runtime.h>

#define N_NODES 8000
#define FEAT 64
#define HID 128
#define LOOKBACK 12
#define CAP 64

// ---------------- front kernel: zero cnt + weight stacking + init encoder ----------------
// 500 blocks. All three sub-jobs are independent of build (which follows in
// stream order): threads 0-15 zero the block's 16 cnt entries; gid<32768 also
// writes one stacked-weight element; all threads run the R12 init body.
__global__ __launch_bounds__(256)
void front_kernel(int* __restrict__ cnt,
                  const float* __restrict__ x,
                  const float* __restrict__ We1, const float* __restrict__ be1,
                  const float* __restrict__ We2, const float* __restrict__ be2,
                  float* __restrict__ out0,
                  const float* __restrict__ Wl1, const float* __restrict__ Wr1,
                  const float* __restrict__ Wl2, const float* __restrict__ Wr2,
                  float* __restrict__ Ws1, float* __restrict__ Wc2) {
    __shared__ float sW1T[HID * LOOKBACK];   // [h][l]
    __shared__ float sB1[HID];
    __shared__ float sW2[HID];
    const int tid = threadIdx.x;
    if (tid < 16) cnt[blockIdx.x * 16 + tid] = 0;
    {   // stack weights: gid over 128000 threads, first 2*16384 do one elem each
        const int gid = blockIdx.x * 256 + tid;
        if (gid < 128 * 128) {              // Ws1[k][j] = [Wl1;Wr1] row-stacked
            int k = gid >> 7, j = gid & 127;
            Ws1[gid] = (k < 64) ? Wl1[k * 128 + j] : Wr1[(k - 64) * 128 + j];
        } else if (gid < 2 * 128 * 128) {   // Wc2[k][j] = [Wl2 | Wr2] col-stacked
            int w = gid - 128 * 128;
            int k = w >> 7, j = w & 127;
            Wc2[w] = (j < 64) ? Wl2[k * 64 + j] : Wr2[k * 64 + (j - 64)];
        }
    }
    for (int e = tid; e < HID * LOOKBACK; e += 256) {
        int l = e / HID, h = e % HID;
        sW1T[h * LOOKBACK + l] = We1[e];
    }
    for (int e = tid; e < HID; e += 256) { sB1[e] = be1[e]; sW2[e] = We2[e]; }
    __syncthreads();
    int g = (blockIdx.x * 256 + tid) * 4;    // 500*256*4 == N*F exactly
    float xv[4][LOOKBACK];
    #pragma unroll
    for (int l = 0; l < LOOKBACK; ++l) {
        float4 v = *reinterpret_cast<const float4*>(x + (long)l * N_NODES * FEAT + g);
        xv[0][l] = v.x; xv[1][l] = v.y; xv[2][l] = v.z; xv[3][l] = v.w;
    }
    float b2 = be2[0];
    float acc[4] = {b2, b2, b2, b2};
    for (int h = 0; h < HID; ++h) {
        float s0 = sB1[h], s1 = s0, s2 = s0, s3 = s0;
        #pragma unroll
        for (int l = 0; l < LOOKBACK; ++l) {
            float w = sW1T[h * LOOKBACK + l];
            s0 += xv[0][l] * w; s1 += xv[1][l] * w;
            s2 += xv[2][l] * w; s3 += xv[3][l] * w;
        }
        float w2 = sW2[h];
        acc[0] += fmaxf(s0, 0.0f) * w2; acc[1] += fmaxf(s1, 0.0f) * w2;
        acc[2] += fmaxf(s2, 0.0f) * w2; acc[3] += fmaxf(s3, 0.0f) * w2;
    }
    float4 o = {acc[0], acc[1], acc[2], acc[3]};
    *reinterpret_cast<float4*>(out0 + g) = o;
}

// ---------------- adjacency extraction: stream-then-drain (R18, 246-verified) ----
__global__ __launch_bounds__(256)
void build_adj_kernel(const float* __restrict__ adj, int* __restrict__ cnt,
                      int* __restrict__ lists) {
    const long NQ = (long)N_NODES * N_NODES / 4;     // 16,000,000 float4s
    const long STRIDE = 2048L * 256;                 // 524,288 threads
    const long t = (long)blockIdx.x * 256 + threadIdx.x;

    int lc = 0;
    int e0 = 0, e1 = 0, e2 = 0, e3 = 0, e4 = 0;
    int e5 = 0, e6 = 0, e7 = 0, e8 = 0, e9 = 0;

    #pragma unroll 1
    for (long q = t; q < NQ; q += STRIDE) {
        float4 w = *reinterpret_cast<const float4*>(adj + 4 * q);
        if (w.x != 0.0f || w.y != 0.0f || w.z != 0.0f || w.w != 0.0f) {
            float wv[4] = {w.x, w.y, w.z, w.w};
            #pragma unroll
            for (int c = 0; c < 4; ++c) {
                if (wv[c] != 0.0f) {
                    int e = (int)(q * 4 + c);        // linear elem idx = i*8000+j
                    if      (lc == 0) e0 = e;
                    else if (lc == 1) e1 = e;
                    else if (lc == 2) e2 = e;
                    else if (lc == 3) e3 = e;
                    else if (lc == 4) e4 = e;
                    else if (lc == 5) e5 = e;
                    else if (lc == 6) e6 = e;
                    else if (lc == 7) e7 = e;
                    else if (lc == 8) e8 = e;
                    else if (lc == 9) e9 = e;
                    ++lc;
                }
            }
        }
    }
    #define DRAIN(K, EK)                                                     \
        if (lc > K) {                                                        \
            int ii = (EK) / N_NODES;                                         \
            int jj = (EK) % N_NODES;                                         \
            int p = atomicAdd(&cnt[jj], 1);                                  \
            if (p < CAP) lists[(long)jj * CAP + p] = ii;                     \
        }
    DRAIN(0, e0) DRAIN(1, e1) DRAIN(2, e2) DRAIN(3, e3) DRAIN(4, e4)
    DRAIN(5, e5) DRAIN(6, e6) DRAIN(7, e7) DRAIN(8, e8) DRAIN(9, e9)
    #undef DRAIN
}

// ---------------- fused SAGE1 + proj + selfMLP (R12 verbatim + step-0 sort) ----
__global__ __launch_bounds__(256)
void sageproj_kernel(const float* __restrict__ h,
                     int* __restrict__ lists, int* __restrict__ cnt,
                     float* __restrict__ degf, int do_sort,
                     const float* __restrict__ Ws1, const float* __restrict__ bl1,
                     const float* __restrict__ Wc2, const float* __restrict__ bl2,
                     const float* __restrict__ Wf1, const float* __restrict__ bf1,
                     const float* __restrict__ Wf2, const float* __restrict__ bf2,
                     float* __restrict__ pl, float* __restrict__ q) {
    __shared__ float v[16][132];     // [node][k]: k<64 aggr, k>=64 h row
    __shared__ float rr[16][132];    // r1
    __shared__ float tt[16][132];    // t = relu(h@Wf1+bf1)
    __shared__ float xsl[16][68];    // xs
    __shared__ float wbuf[64 * 128]; // 32 KB weight panel chunk
    const int tid = threadIdx.x;
    const int nb = blockIdx.x * 16;
    if (do_sort) {                   // canonicalize own 16 nodes (R16-proven)
        const int wv = tid >> 6, lane = tid & 63;
        #pragma unroll 1
        for (int r = 0; r < 4; ++r) {
            const int n = nb + wv * 4 + r;
            int m = cnt[n]; if (m > CAP) m = CAP;
            int val = (lane < m) ? lists[(long)n * CAP + lane] : 0x7FFFFFFF;
            #pragma unroll
            for (int k = 2; k <= 64; k <<= 1) {
                #pragma unroll
                for (int j = k >> 1; j > 0; j >>= 1) {
                    int other = __shfl_xor(val, j);
                    bool keepMin = (((lane & j) == 0) == ((lane & k) == 0));
                    int mn = val < other ? val : other;
                    int mx = val < other ? other : val;
                    val = keepMin ? mn : mx;
                }
            }
            lists[(long)n * CAP + lane] = val;
            if (lane == 0) { cnt[n] = m; degf[n] = (float)(m > 0 ? m : 1); }
        }
        __syncthreads();
    }
    const int ln = tid >> 4, jg = tid & 15;
    const int n = nb + ln;
    const int c0 = jg * 4;
    {   // gather: 16 threads/node, 4 feats each
        const int m = cnt[n];
        const int* l = lists + (long)n * CAP;
        const float inv = 1.0f / degf[n];
        float4 a = {0, 0, 0, 0};
        for (int e = 0; e < m; ++e) {
            float4 b = *reinterpret_cast<const float4*>(h + (long)l[e] * FEAT + c0);
            a.x += b.x; a.y += b.y; a.z += b.z; a.w += b.w;
        }
        float4 av = {a.x * inv, a.y * inv, a.z * inv, a.w * inv};
        *reinterpret_cast<float4*>(&v[ln][c0]) = av;
        *reinterpret_cast<float4*>(&v[ln][64 + c0]) =
            *reinterpret_cast<const float4*>(h + (long)n * FEAT + c0);
    }
    // ---- P1: rr = relu([aggr|h] @ Ws1 + bl1), K=128 in 2 chunks ----
    {
        float4 b0 = *reinterpret_cast<const float4*>(bl1 + c0);
        float4 b1 = *reinterpret_cast<const float4*>(bl1 + 64 + c0);
        float A0[4] = {b0.x, b0.y, b0.z, b0.w};
        float A1[4] = {b1.x, b1.y, b1.z, b1.w};
        for (int kc = 0; kc < 2; ++kc) {
            __syncthreads();                     // prev consumers done / v ready
            for (int e = tid; e < 2048; e += 256)
                *(reinterpret_cast<float4*>(wbuf) + e) =
                    *(reinterpret_cast<const float4*>(Ws1 + kc * 8192) + e);
            __syncthreads();
            #pragma unroll 4
            for (int k = 0; k < 64; ++k) {
                float a = v[ln][kc * 64 + k];
                float4 w0 = *reinterpret_cast<const float4*>(&wbuf[k * 128 + c0]);
                float4 w1 = *reinterpret_cast<const float4*>(&wbuf[k * 128 + 64 + c0]);
                A0[0] += a * w0.x; A0[1] += a * w0.y; A0[2] += a * w0.z; A0[3] += a * w0.w;
                A1[0] += a * w1.x; A1[1] += a * w1.y; A1[2] += a * w1.z; A1[3] += a * w1.w;
            }
        }
        float4 o0 = {fmaxf(A0[0],0.f), fmaxf(A0[1],0.f), fmaxf(A0[2],0.f), fmaxf(A0[3],0.f)};
        float4 o1 = {fmaxf(A1[0],0.f), fmaxf(A1[1],0.f), fmaxf(A1[2],0.f), fmaxf(A1[3],0.f)};
        *reinterpret_cast<float4*>(&rr[ln][c0]) = o0;
        *reinterpret_cast<float4*>(&rr[ln][64 + c0]) = o1;
    }
    // ---- P2: tt = relu(h @ Wf1 + bf1), K=64, one chunk ----
    {
        float4 b0 = *reinterpret_cast<const float4*>(bf1 + c0);
        float4 b1 = *reinterpret_cast<const float4*>(bf1 + 64 + c0);
        float A0[4] = {b0.x, b0.y, b0.z, b0.w};
        float A1[4] = {b1.x, b1.y, b1.z, b1.w};
        __syncthreads();
        for (int e = tid; e < 2048; e += 256)
            *(reinterpret_cast<float4*>(wbuf) + e) =
                *(reinterpret_cast<const float4*>(Wf1) + e);
        __syncthreads();
        #pragma unroll 4
        for (int k = 0; k < 64; ++k) {
            float a = v[ln][64 + k];
            float4 w0 = *reinterpret_cast<const float4*>(&wbuf[k * 128 + c0]);
            float4 w1 = *reinterpret_cast<const float4*>(&wbuf[k * 128 + 64 + c0]);
            A0[0] += a * w0.x; A0[1] += a * w0.y; A0[2] += a * w0.z; A0[3] += a * w0.w;
            A1[0] += a * w1.x; A1[1] += a * w1.y; A1[2] += a * w1.z; A1[3] += a * w1.w;
        }
        float4 o0 = {fmaxf(A0[0],0.f), fmaxf(A0[1],0.f), fmaxf(A0[2],0.f), fmaxf(A0[3],0.f)};
        float4 o1 = {fmaxf(A1[0],0.f), fmaxf(A1[1],0.f), fmaxf(A1[2],0.f), fmaxf(A1[3],0.f)};
        *reinterpret_cast<float4*>(&tt[ln][c0]) = o0;
        *reinterpret_cast<float4*>(&tt[ln][64 + c0]) = o1;
    }
    // ---- P3: xsl = tt @ Wf2 + bf2, K=128, 64 cols (Wf2 = [128][64]) ----
    {
        float4 b0 = *reinterpret_cast<const float4*>(bf2 + c0);
        float X[4] = {b0.x, b0.y, b0.z, b0.w};
        __syncthreads();
        for (int e = tid; e < 2048; e += 256)
            *(reinterpret_cast<float4*>(wbuf) + e) =
                *(reinterpret_cast<const float4*>(Wf2) + e);
        __syncthreads();
        #pragma unroll 4
        for (int k = 0; k < 128; ++k) {
            float a = tt[ln][k];
            float4 w = *reinterpret_cast<const float4*>(&wbuf[k * 64 + c0]);
            X[0] += a * w.x; X[1] += a * w.y; X[2] += a * w.z; X[3] += a * w.w;
        }
        float4 o = {X[0], X[1], X[2], X[3]};
        *reinterpret_cast<float4*>(&xsl[ln][c0]) = o;
    }
    // ---- P4: [pl|q] = rr @ Wc2 (+ bl2 + xsl on q half), K=128 in 2 chunks ----
    {
        float P0[4] = {0, 0, 0, 0};
        float P1[4] = {0, 0, 0, 0};
        for (int kc = 0; kc < 2; ++kc) {
            __syncthreads();
            for (int e = tid; e < 2048; e += 256)
                *(reinterpret_cast<float4*>(wbuf) + e) =
                    *(reinterpret_cast<const float4*>(Wc2 + kc * 8192) + e);
            __syncthreads();
            #pragma unroll 4
            for (int k = 0; k < 64; ++k) {
                float a = rr[ln][kc * 64 + k];
                float4 w0 = *reinterpret_cast<const float4*>(&wbuf[k * 128 + c0]);
                float4 w1 = *reinterpret_cast<const float4*>(&wbuf[k * 128 + 64 + c0]);
                P0[0] += a * w0.x; P0[1] += a * w0.y; P0[2] += a * w0.z; P0[3] += a * w0.w;
                P1[0] += a * w1.x; P1[1] += a * w1.y; P1[2] += a * w1.z; P1[3] += a * w1.w;
            }
        }
        float4 op = {P0[0], P0[1], P0[2], P0[3]};
        *reinterpret_cast<float4*>(pl + (long)n * FEAT + c0) = op;
        float4 bv = *reinterpret_cast<const float4*>(bl2 + c0);
        float4 oq = {P1[0] + bv.x + xsl[ln][c0 + 0],
                     P1[1] + bv.y + xsl[ln][c0 + 1],
                     P1[2] + bv.z + xsl[ln][c0 + 2],
                     P1[3] + bv.w + xsl[ln][c0 + 3]};
        *reinterpret_cast<float4*>(q + (long)n * FEAT + c0) = oq;
    }
}

// ---------------- gather + Euler epilogue (R12 verbatim) ----------------
__global__ __launch_bounds__(256)
void epi_kernel(const float* __restrict__ pl, const float* __restrict__ q,
                const int* __restrict__ lists, const int* __restrict__ cnt,
                const float* __restrict__ degf, const float* __restrict__ hcur,
                const float* __restrict__ tspan, int step,
                float* __restrict__ hnext) {
    const int tid = threadIdx.x;
    const int ln = tid >> 4, sub = tid & 15;
    const int n = blockIdx.x * 16 + ln;
    const int f0 = sub * 4;
    const int m = cnt[n];
    const int* l = lists + (long)n * CAP;
    const float inv = 1.0f / degf[n];
    float4 a = {0, 0, 0, 0};
    for (int e = 0; e < m; ++e) {
        float4 b = *reinterpret_cast<const float4*>(pl + (long)l[e] * FEAT + f0);
        a.x += b.x; a.y += b.y; a.z += b.z; a.w += b.w;
    }
    const float dt = tspan[step + 1] - tspan[step];
    float4 qv = *reinterpret_cast<const float4*>(q + (long)n * FEAT + f0);
    float4 hv = *reinterpret_cast<const float4*>(hcur + (long)n * FEAT + f0);
    float s0 = qv.x + a.x * inv, s1 = qv.y + a.y * inv;
    float s2 = qv.z + a.z * inv, s3 = qv.w + a.w * inv;
    s0 = fminf(fmaxf(s0, -1000.f), 1000.f); s1 = fminf(fmaxf(s1, -1000.f), 1000.f);
    s2 = fminf(fmaxf(s2, -1000.f), 1000.f); s3 = fminf(fmaxf(s3, -1000.f), 1000.f);
    float4 o = {hv.x + dt * s0, hv.y + dt * s1, hv.z + dt * s2, hv.w + dt * s3};
    *reinterpret_cast<float4*>(hnext + (long)n * FEAT + f0) = o;
}

extern "C" void kernel_launch(void* const* d_in, const int* in_sizes, int n_in,
                              void* d_out, int out_size, void* d_ws, size_t ws_size,
                              hipStream_t stream) {
    const float* tspan = (const float*)d_in[0];
    const float* x     = (const float*)d_in[1];
    const float* adj   = (const float*)d_in[2];
    const float* We1   = (const float*)d_in[3];
    const float* be1   = (const float*)d_in[4];
    const float* We2   = (const float*)d_in[5];
    const float* be2   = (const float*)d_in[6];
    const float* Wf1   = (const float*)d_in[7];
    const float* bf1   = (const float*)d_in[8];
    const float* Wf2   = (const float*)d_in[9];
    const float* bf2   = (const float*)d_in[10];
    const float* Wl1   = (const float*)d_in[11];
    const float* bl1   = (const float*)d_in[12];
    const float* Wr1   = (const float*)d_in[13];
    const float* Wl2   = (const float*)d_in[14];
    const float* bl2   = (const float*)d_in[15];
    const float* Wr2   = (const float*)d_in[16];
    float* out = (float*)d_out;

    // workspace layout (bytes)
    char* ws = (char*)d_ws;
    int*   lists = (int*)  (ws + 0);           // 8000*64*4  = 2,048,000
    int*   cnt   = (int*)  (ws + 2048000);     // 32,000
    float* degf  = (float*)(ws + 2080000);     // 32,000
    float* Ws1   = (float*)(ws + 2112000);     // 65,536
    float* Wc2   = (float*)(ws + 2177536);     // 65,536
    float* pl    = (float*)(ws + 2243072);     // 2,048,000
    float* q     = (float*)(ws + 4291072);     // 2,048,000
    // total 6,339,072 bytes

    front_kernel<<<500, 256, 0, stream>>>(cnt, x, We1, be1, We2, be2, out,
                                          Wl1, Wr1, Wl2, Wr2, Ws1, Wc2);
    build_adj_kernel<<<2048, 256, 0, stream>>>(adj, cnt, lists);

    for (int s = 0; s < 3; ++s) {
        const float* hcur  = out + (long)s       * N_NODES * FEAT;
        float*       hnext = out + (long)(s + 1) * N_NODES * FEAT;
        sageproj_kernel<<<500, 256, 0, stream>>>(hcur, lists, cnt, degf, (s == 0) ? 1 : 0,
                                                 Ws1, bl1, Wc2, bl2,
                                                 Wf1, bf1, Wf2, bf2, pl, q);
        epi_kernel<<<500, 256, 0, stream>>>(pl, q, lists, cnt, degf, hcur, tspan, s, hnext);
    }
}